// Round 1
// baseline (1106.832 us; speedup 1.0000x reference)
//
#include <hip/hip_runtime.h>
#include <stdint.h>

typedef unsigned short u16;
typedef u16 u16x4 __attribute__((ext_vector_type(4)));
typedef u16 u16x8 __attribute__((ext_vector_type(8)));
typedef __bf16 bf16x8 __attribute__((ext_vector_type(8)));
typedef float f32x4 __attribute__((ext_vector_type(4)));

#define MFMA16 __builtin_amdgcn_mfma_f32_16x16x32_bf16

static __device__ __forceinline__ float b2f(u16 u) {
    union { unsigned int i; float f; } v; v.i = ((unsigned int)u) << 16; return v.f;
}
static __device__ __forceinline__ u16 f2b(float f) {
    union { float f; unsigned int i; } v; v.f = f;
    unsigned int r = (v.i + 0x7fffu + ((v.i >> 16) & 1u)) >> 16;
    return (u16)r;
}
static __device__ __forceinline__ void gload_lds16(const void* g, void* l) {
    __builtin_amdgcn_global_load_lds((__attribute__((address_space(1))) void*)g,
                                     (__attribute__((address_space(3))) void*)l,
                                     16, 0, 0);
}

// ---------------- fp32 -> bf16 weight conversion ----------------
__global__ __launch_bounds__(256) void cvt_k(const float* __restrict__ in,
                                             u16* __restrict__ out, long n) {
    long i = ((long)blockIdx.x * 256 + threadIdx.x) * 4;
    if (i >= n) return;
    float4 v = *(const float4*)(in + i);
    u16x4 o; o[0] = f2b(v.x); o[1] = f2b(v.y); o[2] = f2b(v.z); o[3] = f2b(v.w);
    *(u16x4*)(out + i) = o;
}

// ---------------- RMSNorm: fp32 in -> bf16 out (D=2048, one block per row) ----
__global__ __launch_bounds__(256) void rmsnorm_k(const float* __restrict__ x,
                                                 const float* __restrict__ g,
                                                 u16* __restrict__ out) {
    const long row = blockIdx.x;
    const int tid = threadIdx.x;
    const float* xr = x + row * 2048;
    float4 a = *(const float4*)(xr + tid * 4);
    float4 b = *(const float4*)(xr + 1024 + tid * 4);
    float ss = a.x*a.x + a.y*a.y + a.z*a.z + a.w*a.w
             + b.x*b.x + b.y*b.y + b.z*b.z + b.w*b.w;
    #pragma unroll
    for (int d = 1; d < 64; d <<= 1) ss += __shfl_xor(ss, d);
    __shared__ float red[4];
    if ((tid & 63) == 0) red[tid >> 6] = ss;
    __syncthreads();
    float tot = red[0] + red[1] + red[2] + red[3];
    float rinv = rsqrtf(tot * (1.0f / 2048.0f) + 1e-6f);
    float4 g0 = *(const float4*)(g + tid * 4);
    float4 g1 = *(const float4*)(g + 1024 + tid * 4);
    u16x4 o0, o1;
    o0[0] = f2b(a.x * g0.x * rinv); o0[1] = f2b(a.y * g0.y * rinv);
    o0[2] = f2b(a.z * g0.z * rinv); o0[3] = f2b(a.w * g0.w * rinv);
    o1[0] = f2b(b.x * g1.x * rinv); o1[1] = f2b(b.y * g1.y * rinv);
    o1[2] = f2b(b.z * g1.z * rinv); o1[3] = f2b(b.w * g1.w * rinv);
    *(u16x4*)(out + row * 2048 + tid * 4) = o0;
    *(u16x4*)(out + row * 2048 + 1024 + tid * 4) = o1;
}

// ---------------- RoPE in-place on bf16 qkv; q additionally scaled ------------
__global__ __launch_bounds__(256) void rope_k(u16* __restrict__ qkv,
                                              const float* __restrict__ cosb,
                                              const float* __restrict__ sinb) {
    long idx = (long)blockIdx.x * 256 + threadIdx.x; // < 4096*2*16*16
    int d = (int)(idx & 15) * 4;
    int h = (int)((idx >> 4) & 15);
    int which = (int)((idx >> 8) & 1);
    long row = idx >> 9;                 // 0..4095 (= b*2048+s)
    int s = (int)(row & 2047);
    u16* base = qkv + row * 6144 + which * 2048 + h * 128;
    u16x4 ua = *(u16x4*)(base + d);
    u16x4 ub = *(u16x4*)(base + d + 64);
    float4 c4 = *(const float4*)(cosb + (long)s * 128 + d);
    float4 s4 = *(const float4*)(sinb + (long)s * 128 + d);
    float cc[4] = {c4.x, c4.y, c4.z, c4.w};
    float sn[4] = {s4.x, s4.y, s4.z, s4.w};
    float scale = (which == 0) ? 0.08838834764831845f : 1.0f;
    u16x4 oa, ob;
    #pragma unroll
    for (int j = 0; j < 4; ++j) {
        float a = b2f(ua[j]), b = b2f(ub[j]);
        oa[j] = f2b((a * cc[j] - b * sn[j]) * scale);
        ob[j] = f2b((b * cc[j] + a * sn[j]) * scale);
    }
    *(u16x4*)(base + d) = oa;
    *(u16x4*)(base + d + 64) = ob;
}

// ---------------- GEMM: C[M,N] = A[M,K] @ W[N,K]^T  (m97 structure) -----------
// EPI: 0 = bf16 out, 1 = fp32 out with +res, 2 = gelu(tanh) bf16 out
template <int EPI>
__global__ __launch_bounds__(256) void gemm_bt(const u16* __restrict__ A,
                                               const u16* __restrict__ W,
                                               int M, int N, int K,
                                               u16* outb, float* outf,
                                               const float* res) {
    __shared__ u16 As[128 * 32];
    __shared__ u16 Bs[128 * 32];
    const int tid = threadIdx.x;
    const int wave = tid >> 6, lane = tid & 63;
    const int wr = wave >> 1, wc = wave & 1;
    const int bm = blockIdx.y, bn = blockIdx.x;
    const int l4 = lane >> 2;          // 0..15
    const int c8 = (lane & 3) * 8;     // k elem offset
    const long arow0 = (long)bm * 128;
    const long brow0 = (long)bn * 128;

    f32x4 acc[4][4];
    #pragma unroll
    for (int m = 0; m < 4; ++m)
        #pragma unroll
        for (int n = 0; n < 4; ++n) acc[m][n] = (f32x4){0.f, 0.f, 0.f, 0.f};

    const int nk = K >> 5;
    for (int kt = 0; kt < nk; ++kt) {
        __syncthreads();
        #pragma unroll
        for (int p = 0; p < 2; ++p) {
            int row = p * 64 + wave * 16 + l4;
            const u16* ga = A + (arow0 + row) * (long)K + kt * 32 + c8;
            gload_lds16(ga, (char*)As + p * 4096 + wave * 1024);
            const u16* gb = W + (brow0 + row) * (long)K + kt * 32 + c8;
            gload_lds16(gb, (char*)Bs + p * 4096 + wave * 1024);
        }
        __syncthreads();
        bf16x8 af[4], bfr[4];
        #pragma unroll
        for (int m = 0; m < 4; ++m)
            af[m] = *(const bf16x8*)((const char*)As +
                     (wr * 64 + m * 16 + (lane & 15)) * 64 + (lane >> 4) * 16);
        #pragma unroll
        for (int n = 0; n < 4; ++n)
            bfr[n] = *(const bf16x8*)((const char*)Bs +
                     (wc * 64 + n * 16 + (lane & 15)) * 64 + (lane >> 4) * 16);
        #pragma unroll
        for (int m = 0; m < 4; ++m)
            #pragma unroll
            for (int n = 0; n < 4; ++n)
                acc[m][n] = MFMA16(af[m], bfr[n], acc[m][n], 0, 0, 0);
    }

    const int rb = bm * 128 + wr * 64 + ((lane >> 4) << 2);
    const int cb = bn * 128 + wc * 64 + (lane & 15);
    #pragma unroll
    for (int m = 0; m < 4; ++m) {
        #pragma unroll
        for (int r = 0; r < 4; ++r) {
            long row = rb + m * 16 + r;
            #pragma unroll
            for (int n = 0; n < 4; ++n) {
                long col = cb + n * 16;
                float v = acc[m][n][r];
                if (EPI == 1) {
                    outf[row * N + col] = res[row * N + col] + v;
                } else if (EPI == 2) {
                    float u = 0.7978845608028654f * v * (1.0f + 0.044715f * v * v);
                    float e = __expf(2.0f * u);
                    float t = 1.0f - 2.0f / (e + 1.0f);
                    outb[row * N + col] = f2b(0.5f * v * (1.0f + t));
                } else {
                    outb[row * N + col] = f2b(v);
                }
            }
        }
    }
}

// ---------------- causal flash attention ------------------------------------
// grid: (S/64, B*H). 4 waves/block; wave owns 16 q rows. KVBLK=32.
__global__ __launch_bounds__(256) void attn_k(const u16* __restrict__ qkv,
                                              u16* __restrict__ out) {
    const int bh = blockIdx.y;
    const int b = bh >> 4, h = bh & 15;
    const int q0 = blockIdx.x * 64;
    const int tid = threadIdx.x, wave = tid >> 6, lane = tid & 63;
    const int g16 = lane >> 4;    // 0..3
    const int l16 = lane & 15;
    __shared__ u16 Ks[32 * 128];  // [kv][d], d-slot XOR (kv&7) swizzle
    __shared__ u16 Vt[128 * 32];  // [d][kv], kv-slot XOR ((d>>1)&3) swizzle
    __shared__ u16 Ps[4][16 * 32];// per wave [row][kv], kv-slot XOR ((row>>1)&3)

    const int r0 = q0 + wave * 16;
    // Q fragments (already roped + pre-scaled by 1/sqrt(HD))
    bf16x8 qf[4];
    {
        const u16* qp = qkv + (long)(b * 2048 + r0 + l16) * 6144 + h * 128 + g16 * 8;
        #pragma unroll
        for (int kk = 0; kk < 4; ++kk) qf[kk] = *(const bf16x8*)(qp + kk * 32);
    }
    float m_i[4] = {-INFINITY, -INFINITY, -INFINITY, -INFINITY};
    float l_i[4] = {0.f, 0.f, 0.f, 0.f};
    f32x4 o[8];
    #pragma unroll
    for (int i = 0; i < 8; ++i) o[i] = (f32x4){0.f, 0.f, 0.f, 0.f};

    const int ntiles = (q0 + 64) >> 5;
    for (int t = 0; t < ntiles; ++t) {
        const int kv0 = t << 5;
        __syncthreads();
        // stage K with swizzled global source (linear LDS dest)
        #pragma unroll
        for (int p = 0; p < 2; ++p) {
            int flat16 = p * 256 + wave * 64 + lane;
            int kv = flat16 >> 4;
            int slot = flat16 & 15;
            int srcslot = slot ^ (kv & 7);
            const u16* gk = qkv + (long)(b * 2048 + kv0 + kv) * 6144 + 2048 +
                            h * 128 + srcslot * 8;
            gload_lds16(gk, (char*)Ks + p * 4096 + wave * 1024);
        }
        // stage V transposed (reg-staged, swizzled kv-slot)
        #pragma unroll
        for (int p = 0; p < 2; ++p) {
            int flat16 = p * 256 + tid;
            int kv = flat16 >> 4;
            int d0 = (flat16 & 15) * 8;
            const u16* gv = qkv + (long)(b * 2048 + kv0 + kv) * 6144 + 4096 +
                            h * 128 + d0;
            u16x8 v = *(const u16x8*)gv;
            #pragma unroll
            for (int j = 0; j < 8; ++j) {
                int d = d0 + j;
                int slot = (kv >> 3) ^ ((d >> 1) & 3);
                *(u16*)((char*)Vt + d * 64 + slot * 16 + (kv & 7) * 2) = v[j];
            }
        }
        __syncthreads();
        if (kv0 <= r0 + 15) {
            f32x4 s[2];
            s[0] = (f32x4){0.f, 0.f, 0.f, 0.f};
            s[1] = (f32x4){0.f, 0.f, 0.f, 0.f};
            #pragma unroll
            for (int tt = 0; tt < 2; ++tt) {
                int kv = tt * 16 + l16;
                #pragma unroll
                for (int kk = 0; kk < 4; ++kk) {
                    int dslot = kk * 4 + g16;
                    bf16x8 kf = *(const bf16x8*)((const char*)Ks + kv * 256 +
                                 (dslot ^ (kv & 7)) * 16);
                    s[tt] = MFMA16(qf[kk], kf, s[tt], 0, 0, 0);
                }
            }
            float p8[2][4];
            #pragma unroll
            for (int tt = 0; tt < 2; ++tt) {
                int kvg = kv0 + tt * 16 + l16;
                #pragma unroll
                for (int r = 0; r < 4; ++r) {
                    int qg = r0 + g16 * 4 + r;
                    p8[tt][r] = (kvg <= qg) ? s[tt][r] : -INFINITY;
                }
            }
            float mx[4];
            #pragma unroll
            for (int r = 0; r < 4; ++r) mx[r] = fmaxf(p8[0][r], p8[1][r]);
            #pragma unroll
            for (int dd = 1; dd < 16; dd <<= 1)
                #pragma unroll
                for (int r = 0; r < 4; ++r)
                    mx[r] = fmaxf(mx[r], __shfl_xor(mx[r], dd));
            float f[4], rs[4];
            #pragma unroll
            for (int r = 0; r < 4; ++r) {
                float mnew = fmaxf(m_i[r], mx[r]);
                f[r] = __expf(m_i[r] - mnew);
                m_i[r] = mnew;
                p8[0][r] = __expf(p8[0][r] - mnew);
                p8[1][r] = __expf(p8[1][r] - mnew);
                rs[r] = p8[0][r] + p8[1][r];
            }
            #pragma unroll
            for (int dd = 1; dd < 16; dd <<= 1)
                #pragma unroll
                for (int r = 0; r < 4; ++r) rs[r] += __shfl_xor(rs[r], dd);
            #pragma unroll
            for (int r = 0; r < 4; ++r) l_i[r] = l_i[r] * f[r] + rs[r];
            #pragma unroll
            for (int dt = 0; dt < 8; ++dt)
                #pragma unroll
                for (int r = 0; r < 4; ++r) o[dt][r] *= f[r];
            // write P (D-layout -> LDS), wave-private
            #pragma unroll
            for (int tt = 0; tt < 2; ++tt)
                #pragma unroll
                for (int r = 0; r < 4; ++r) {
                    int rowp = g16 * 4 + r;
                    int kv = tt * 16 + l16;
                    int slot = (kv >> 3) ^ ((rowp >> 1) & 3);
                    *(u16*)((char*)&Ps[wave][0] + rowp * 64 + slot * 16 +
                            (kv & 7) * 2) = f2b(p8[tt][r]);
                }
            // read P as A-fragment
            bf16x8 pf;
            {
                int rowp = l16;
                int slot = g16 ^ ((rowp >> 1) & 3);
                pf = *(const bf16x8*)((const char*)&Ps[wave][0] + rowp * 64 +
                                      slot * 16);
            }
            #pragma unroll
            for (int dt = 0; dt < 8; ++dt) {
                int d = dt * 16 + l16;
                int slot = g16 ^ ((d >> 1) & 3);
                bf16x8 vf = *(const bf16x8*)((const char*)Vt + d * 64 + slot * 16);
                o[dt] = MFMA16(pf, vf, o[dt], 0, 0, 0);
            }
        }
    }
    #pragma unroll
    for (int r = 0; r < 4; ++r) {
        float inv = 1.0f / l_i[r];
        long row = (long)(b * 2048 + r0 + g16 * 4 + r);
        #pragma unroll
        for (int dt = 0; dt < 8; ++dt)
            out[row * 2048 + h * 128 + dt * 16 + l16] = f2b(o[dt][r] * inv);
    }
}

// ---------------- launch --------------------------------------------------
extern "C" void kernel_launch(void* const* d_in, const int* in_sizes, int n_in,
                              void* d_out, int out_size, void* d_ws, size_t ws_size,
                              hipStream_t stream) {
    const float* x     = (const float*)d_in[0];
    const float* cosb  = (const float*)d_in[1];
    const float* sinb  = (const float*)d_in[2];
    const float* g1    = (const float*)d_in[3];
    const float* g2    = (const float*)d_in[4];
    const float* w_qkv = (const float*)d_in[5];
    const float* w_out = (const float*)d_in[6];
    const float* w_fc1 = (const float*)d_in[7];
    const float* w_fc2 = (const float*)d_in[8];

    char* ws = (char*)d_ws;
    u16* wqkv_b = (u16*)(ws);                    // 6144x2048 bf16
    u16* wout_b = (u16*)(ws + 25165824);         // 2048x2048
    u16* wfc1_b = (u16*)(ws + 33554432);         // 8192x2048
    u16* wfc2_b = (u16*)(ws + 67108864);         // 2048x8192
    u16* h_b    = (u16*)(ws + 100663296);        // 4096x2048 (h1 then h2)
    u16* qkv_b  = (u16*)(ws + 117440512);        // 4096x6144
    u16* attn_b = (u16*)(ws + 167772160);        // 4096x2048
    u16* hg_b   = qkv_b;                         // 4096x8192, reuses qkv+attn
    float* xout = (float*)d_out;                 // x2 then final

    cvt_k<<<12288, 256, 0, stream>>>(w_qkv, wqkv_b, 12582912L);
    cvt_k<<<4096, 256, 0, stream>>>(w_out, wout_b, 4194304L);
    cvt_k<<<16384, 256, 0, stream>>>(w_fc1, wfc1_b, 16777216L);
    cvt_k<<<16384, 256, 0, stream>>>(w_fc2, wfc2_b, 16777216L);

    rmsnorm_k<<<4096, 256, 0, stream>>>(x, g1, h_b);
    gemm_bt<0><<<dim3(48, 32), 256, 0, stream>>>(h_b, wqkv_b, 4096, 6144, 2048,
                                                 qkv_b, nullptr, nullptr);
    rope_k<<<8192, 256, 0, stream>>>(qkv_b, cosb, sinb);
    attn_k<<<dim3(32, 32), 256, 0, stream>>>(qkv_b, attn_b);
    gemm_bt<1><<<dim3(16, 32), 256, 0, stream>>>(attn_b, wout_b, 4096, 2048, 2048,
                                                 nullptr, xout, x);
    rmsnorm_k<<<4096, 256, 0, stream>>>(xout, g2, h_b);
    gemm_bt<2><<<dim3(64, 32), 256, 0, stream>>>(h_b, wfc1_b, 4096, 8192, 2048,
                                                 hg_b, nullptr, nullptr);
    gemm_bt<1><<<dim3(16, 32), 256, 0, stream>>>(hg_b, wfc2_b, 4096, 2048, 8192,
                                                 nullptr, xout, xout);
}

// Round 2
// 854.445 us; speedup vs baseline: 1.2954x; 1.2954x over previous
//
#include <hip/hip_runtime.h>
#include <stdint.h>

typedef unsigned short u16;
typedef u16 u16x4 __attribute__((ext_vector_type(4)));
typedef u16 u16x8 __attribute__((ext_vector_type(8)));
typedef __bf16 bf16x8 __attribute__((ext_vector_type(8)));
typedef float f32x4 __attribute__((ext_vector_type(4)));
typedef float f32x16 __attribute__((ext_vector_type(16)));

#define MFMA16 __builtin_amdgcn_mfma_f32_16x16x32_bf16
#define MFMA32 __builtin_amdgcn_mfma_f32_32x32x16_bf16

static __device__ __forceinline__ float b2f(u16 u) {
    union { unsigned int i; float f; } v; v.i = ((unsigned int)u) << 16; return v.f;
}
static __device__ __forceinline__ u16 f2b(float f) {
    union { float f; unsigned int i; } v; v.f = f;
    unsigned int r = (v.i + 0x7fffu + ((v.i >> 16) & 1u)) >> 16;
    return (u16)r;
}
static __device__ __forceinline__ unsigned pk2(float lo, float hi) {
    union { __bf16 b[2]; unsigned u; } t;
    t.b[0] = (__bf16)lo; t.b[1] = (__bf16)hi; return t.u;
}
static __device__ __forceinline__ void gload_lds16(const void* g, void* l) {
    __builtin_amdgcn_global_load_lds((__attribute__((address_space(1))) void*)g,
                                     (__attribute__((address_space(3))) void*)l,
                                     16, 0, 0);
}

// ---------------- fp32 -> bf16 weight conversion ----------------
__global__ __launch_bounds__(256) void cvt_k(const float* __restrict__ in,
                                             u16* __restrict__ out, long n) {
    long i = ((long)blockIdx.x * 256 + threadIdx.x) * 4;
    if (i >= n) return;
    float4 v = *(const float4*)(in + i);
    u16x4 o; o[0] = f2b(v.x); o[1] = f2b(v.y); o[2] = f2b(v.z); o[3] = f2b(v.w);
    *(u16x4*)(out + i) = o;
}

// ---------------- RMSNorm: fp32 in -> bf16 out (D=2048) ----------------------
__global__ __launch_bounds__(256) void rmsnorm_k(const float* __restrict__ x,
                                                 const float* __restrict__ g,
                                                 u16* __restrict__ out) {
    const long row = blockIdx.x;
    const int tid = threadIdx.x;
    const float* xr = x + row * 2048;
    float4 a = *(const float4*)(xr + tid * 4);
    float4 b = *(const float4*)(xr + 1024 + tid * 4);
    float ss = a.x*a.x + a.y*a.y + a.z*a.z + a.w*a.w
             + b.x*b.x + b.y*b.y + b.z*b.z + b.w*b.w;
    #pragma unroll
    for (int d = 1; d < 64; d <<= 1) ss += __shfl_xor(ss, d);
    __shared__ float red[4];
    if ((tid & 63) == 0) red[tid >> 6] = ss;
    __syncthreads();
    float tot = red[0] + red[1] + red[2] + red[3];
    float rinv = rsqrtf(tot * (1.0f / 2048.0f) + 1e-6f);
    float4 g0 = *(const float4*)(g + tid * 4);
    float4 g1 = *(const float4*)(g + 1024 + tid * 4);
    u16x4 o0, o1;
    o0[0] = f2b(a.x * g0.x * rinv); o0[1] = f2b(a.y * g0.y * rinv);
    o0[2] = f2b(a.z * g0.z * rinv); o0[3] = f2b(a.w * g0.w * rinv);
    o1[0] = f2b(b.x * g1.x * rinv); o1[1] = f2b(b.y * g1.y * rinv);
    o1[2] = f2b(b.z * g1.z * rinv); o1[3] = f2b(b.w * g1.w * rinv);
    *(u16x4*)(out + row * 2048 + tid * 4) = o0;
    *(u16x4*)(out + row * 2048 + 1024 + tid * 4) = o1;
}

// ---------------- RoPE in-place on bf16 qkv; q additionally scaled ------------
__global__ __launch_bounds__(256) void rope_k(u16* __restrict__ qkv,
                                              const float* __restrict__ cosb,
                                              const float* __restrict__ sinb) {
    long idx = (long)blockIdx.x * 256 + threadIdx.x;
    int d = (int)(idx & 15) * 4;
    int h = (int)((idx >> 4) & 15);
    int which = (int)((idx >> 8) & 1);
    long row = idx >> 9;
    int s = (int)(row & 2047);
    u16* base = qkv + row * 6144 + which * 2048 + h * 128;
    u16x4 ua = *(u16x4*)(base + d);
    u16x4 ub = *(u16x4*)(base + d + 64);
    float4 c4 = *(const float4*)(cosb + (long)s * 128 + d);
    float4 s4 = *(const float4*)(sinb + (long)s * 128 + d);
    float cc[4] = {c4.x, c4.y, c4.z, c4.w};
    float sn[4] = {s4.x, s4.y, s4.z, s4.w};
    float scale = (which == 0) ? 0.08838834764831845f : 1.0f;
    u16x4 oa, ob;
    #pragma unroll
    for (int j = 0; j < 4; ++j) {
        float a = b2f(ua[j]), b = b2f(ub[j]);
        oa[j] = f2b((a * cc[j] - b * sn[j]) * scale);
        ob[j] = f2b((b * cc[j] + a * sn[j]) * scale);
    }
    *(u16x4*)(base + d) = oa;
    *(u16x4*)(base + d + 64) = ob;
}

// ---------------- V transpose: qkv V section -> vt[bh][d][s] -----------------
__global__ __launch_bounds__(256) void vtrans_k(const u16* __restrict__ qkv,
                                                u16* __restrict__ vt) {
    __shared__ u16 t[128 * 65];
    const int bh = blockIdx.y, b = bh >> 4, h = bh & 15;
    const int s0 = blockIdx.x * 64;
    const int tid = threadIdx.x;
    #pragma unroll
    for (int it = 0; it < 4; ++it) {
        int flat = it * 256 + tid;
        int sl = flat >> 4, slot = flat & 15;
        u16x8 v = *(const u16x8*)(qkv + (long)(b * 2048 + s0 + sl) * 6144 + 4096 +
                                  h * 128 + slot * 8);
        #pragma unroll
        for (int j = 0; j < 8; ++j) t[(slot * 8 + j) * 65 + sl] = v[j];
    }
    __syncthreads();
    #pragma unroll
    for (int it = 0; it < 4; ++it) {
        int flat = it * 256 + tid;
        int d = flat >> 3, sg = flat & 7;
        u16x8 v;
        #pragma unroll
        for (int j = 0; j < 8; ++j) v[j] = t[d * 65 + sg * 8 + j];
        *(u16x8*)(vt + ((long)bh * 128 + d) * 2048 + s0 + sg * 8) = v;
    }
}

// ---------------- GEMM: C[M,N] = A[M,K] @ W[N,K]^T  (m97 structure) -----------
template <int EPI>
__global__ __launch_bounds__(256) void gemm_bt(const u16* __restrict__ A,
                                               const u16* __restrict__ W,
                                               int M, int N, int K,
                                               u16* outb, float* outf,
                                               const float* res) {
    __shared__ u16 As[128 * 32];
    __shared__ u16 Bs[128 * 32];
    const int tid = threadIdx.x;
    const int wave = tid >> 6, lane = tid & 63;
    const int wr = wave >> 1, wc = wave & 1;
    const int bm = blockIdx.y, bn = blockIdx.x;
    const int l4 = lane >> 2;
    const int c8 = (lane & 3) * 8;
    const long arow0 = (long)bm * 128;
    const long brow0 = (long)bn * 128;

    f32x4 acc[4][4];
    #pragma unroll
    for (int m = 0; m < 4; ++m)
        #pragma unroll
        for (int n = 0; n < 4; ++n) acc[m][n] = (f32x4){0.f, 0.f, 0.f, 0.f};

    const int nk = K >> 5;
    for (int kt = 0; kt < nk; ++kt) {
        __syncthreads();
        #pragma unroll
        for (int p = 0; p < 2; ++p) {
            int row = p * 64 + wave * 16 + l4;
            const u16* ga = A + (arow0 + row) * (long)K + kt * 32 + c8;
            gload_lds16(ga, (char*)As + p * 4096 + wave * 1024);
            const u16* gb = W + (brow0 + row) * (long)K + kt * 32 + c8;
            gload_lds16(gb, (char*)Bs + p * 4096 + wave * 1024);
        }
        __syncthreads();
        bf16x8 af[4], bfr[4];
        #pragma unroll
        for (int m = 0; m < 4; ++m)
            af[m] = *(const bf16x8*)((const char*)As +
                     (wr * 64 + m * 16 + (lane & 15)) * 64 + (lane >> 4) * 16);
        #pragma unroll
        for (int n = 0; n < 4; ++n)
            bfr[n] = *(const bf16x8*)((const char*)Bs +
                     (wc * 64 + n * 16 + (lane & 15)) * 64 + (lane >> 4) * 16);
        #pragma unroll
        for (int m = 0; m < 4; ++m)
            #pragma unroll
            for (int n = 0; n < 4; ++n)
                acc[m][n] = MFMA16(af[m], bfr[n], acc[m][n], 0, 0, 0);
    }

    const int rb = bm * 128 + wr * 64 + ((lane >> 4) << 2);
    const int cb = bn * 128 + wc * 64 + (lane & 15);
    #pragma unroll
    for (int m = 0; m < 4; ++m) {
        #pragma unroll
        for (int r = 0; r < 4; ++r) {
            long row = rb + m * 16 + r;
            #pragma unroll
            for (int n = 0; n < 4; ++n) {
                long col = cb + n * 16;
                float v = acc[m][n][r];
                if (EPI == 1) {
                    outf[row * N + col] = res[row * N + col] + v;
                } else if (EPI == 2) {
                    float u = 0.7978845608028654f * v * (1.0f + 0.044715f * v * v);
                    float e = __expf(2.0f * u);
                    float t = 1.0f - 2.0f / (e + 1.0f);
                    outb[row * N + col] = f2b(0.5f * v * (1.0f + t));
                } else {
                    outb[row * N + col] = f2b(v);
                }
            }
        }
    }
}

// ---------------- causal flash attention v2 ----------------------------------
// 2 waves/block, each wave owns 32 q rows (QBLK=64), KVBLK=64.
// Swapped QK^T via 32x32x16 MFMA: lane holds P^T[q=lane&31] columns;
// softmax lane-local + one shfl_xor(32); P->A-frag via bf16 pack + shfl;
// O^T accumulation (rescale factor lane-local). K/Vt staged via
// global_load_lds with XOR-swizzled global source, linear LDS dest.
struct AttnState {
    f32x16 acc[4];
    float m_i, l_i;
};

template <bool DIAG>
static __device__ __forceinline__ void attn_tile(
    int kv0, int qg, int wave, int l31, int hi,
    const u16* __restrict__ Ks, const u16* __restrict__ Vt,
    const bf16x8 (&qf)[8], AttnState& st)
{
    const bool do_g1 = !(DIAG && wave == 0);
    f32x16 sacc0, sacc1;
    #pragma unroll
    for (int r = 0; r < 16; ++r) { sacc0[r] = 0.f; sacc1[r] = 0.f; }

    // QK^T swapped: A = K (row=kv), B = Q (col=q)
    #pragma unroll
    for (int dsl = 0; dsl < 8; ++dsl) {
        int slot = dsl * 2 + hi;
        int kv = l31;
        int sw = (slot & 8) | ((slot & 7) ^ (kv & 7));
        bf16x8 kf = *(const bf16x8*)(Ks + kv * 128 + sw * 8);
        sacc0 = MFMA32(kf, qf[dsl], sacc0, 0, 0, 0);
    }
    if (do_g1) {
        #pragma unroll
        for (int dsl = 0; dsl < 8; ++dsl) {
            int slot = dsl * 2 + hi;
            int kv = 32 + l31;
            int sw = (slot & 8) | ((slot & 7) ^ (kv & 7));
            bf16x8 kf = *(const bf16x8*)(Ks + kv * 128 + sw * 8);
            sacc1 = MFMA32(kf, qf[dsl], sacc1, 0, 0, 0);
        }
    }

    // mask + copy to sv
    float sv[2][16];
    #pragma unroll
    for (int r = 0; r < 16; ++r) {
        sv[0][r] = sacc0[r];
        sv[1][r] = do_g1 ? sacc1[r] : -INFINITY;
    }
    if (DIAG) {
        #pragma unroll
        for (int g = 0; g < 2; ++g)
            #pragma unroll
            for (int r = 0; r < 16; ++r) {
                int kvg = kv0 + g * 32 + ((r & 3) + 8 * (r >> 2) + 4 * hi);
                if (kvg > qg) sv[g][r] = -INFINITY;
            }
    }

    // row max (32 in-lane + partner half)
    float mx = sv[0][0];
    #pragma unroll
    for (int r = 1; r < 16; ++r) mx = fmaxf(mx, sv[0][r]);
    #pragma unroll
    for (int r = 0; r < 16; ++r) mx = fmaxf(mx, sv[1][r]);
    mx = fmaxf(mx, __shfl_xor(mx, 32));

    // defer-max (T13, THR=8)
    bool defer = __all(mx <= st.m_i + 8.0f);
    if (!defer) {
        float mnew = fmaxf(st.m_i, mx);
        float f = __expf(st.m_i - mnew);
        st.l_i *= f;
        #pragma unroll
        for (int dblk = 0; dblk < 4; ++dblk)
            #pragma unroll
            for (int r = 0; r < 16; ++r) st.acc[dblk][r] *= f;
        st.m_i = mnew;
    }

    // exp + row sum
    float ssum = 0.f;
    #pragma unroll
    for (int g = 0; g < 2; ++g)
        #pragma unroll
        for (int r = 0; r < 16; ++r) {
            float e = __expf(sv[g][r] - st.m_i);
            sv[g][r] = e;
            ssum += e;
        }
    ssum += __shfl_xor(ssum, 32);
    st.l_i += ssum;

    // P -> A-fragments (bf16 pack + cross-half shfl)
    unsigned w[2][4][2];
    #pragma unroll
    for (int g = 0; g < 2; ++g)
        #pragma unroll
        for (int q4 = 0; q4 < 4; ++q4) {
            w[g][q4][0] = pk2(sv[g][4 * q4 + 0], sv[g][4 * q4 + 1]);
            w[g][q4][1] = pk2(sv[g][4 * q4 + 2], sv[g][4 * q4 + 3]);
        }
    bf16x8 pfrag[4];
    #pragma unroll
    for (int ks = 0; ks < 4; ++ks) {
        int g = ks >> 1, h2 = ks & 1;
        unsigned o0 = hi ? w[g][2 * h2 + 1][0] : w[g][2 * h2][0];
        unsigned o1 = hi ? w[g][2 * h2 + 1][1] : w[g][2 * h2][1];
        unsigned t0 = hi ? w[g][2 * h2][0] : w[g][2 * h2 + 1][0];
        unsigned t1 = hi ? w[g][2 * h2][1] : w[g][2 * h2 + 1][1];
        unsigned s0v = __shfl_xor(t0, 32);
        unsigned s1v = __shfl_xor(t1, 32);
        union { unsigned u[4]; bf16x8 v; } cv;
        cv.u[0] = hi ? s0v : o0;
        cv.u[1] = hi ? s1v : o1;
        cv.u[2] = hi ? o0 : s0v;
        cv.u[3] = hi ? o1 : s1v;
        pfrag[ks] = cv.v;
    }

    // PV: O^T[d][q] += V^T[d][kv] * P[kv][q]
    #pragma unroll
    for (int dblk = 0; dblk < 4; ++dblk) {
        int d = dblk * 32 + l31;
        #pragma unroll
        for (int ks = 0; ks < 4; ++ks) {
            if (ks >= 2 && !do_g1) continue;
            int slot = ks * 2 + hi;
            bf16x8 vf = *(const bf16x8*)(Vt + d * 64 + (slot ^ (d & 7)) * 8);
            st.acc[dblk] = MFMA32(vf, pfrag[ks], st.acc[dblk], 0, 0, 0);
        }
    }
}

__global__ __launch_bounds__(128) void attn2_k(const u16* __restrict__ qkv,
                                               const u16* __restrict__ vt,
                                               u16* __restrict__ out) {
    const int bh = blockIdx.y;
    const int b = bh >> 4, h = bh & 15;
    const int qb = blockIdx.x;
    const int q0 = qb * 64;
    const int tid = threadIdx.x, wave = tid >> 6, lane = tid & 63;
    const int l31 = lane & 31, hi = lane >> 5;
    const int brow = b * 2048;
    __shared__ u16 Ks_lds[64 * 128];
    __shared__ u16 Vt_lds[128 * 64];

    // Q fragments: B[k=d][col=q] -> lane holds Q[q=l31][dsl*16 + hi*8 + j]
    bf16x8 qf[8];
    {
        const u16* qp = qkv + (long)(brow + q0 + wave * 32 + l31) * 6144 +
                        h * 128 + hi * 8;
        #pragma unroll
        for (int dsl = 0; dsl < 8; ++dsl) qf[dsl] = *(const bf16x8*)(qp + dsl * 16);
    }

    AttnState st;
    st.m_i = -INFINITY; st.l_i = 0.f;
    #pragma unroll
    for (int dblk = 0; dblk < 4; ++dblk)
        #pragma unroll
        for (int r = 0; r < 16; ++r) st.acc[dblk][r] = 0.f;

    const int qg = q0 + wave * 32 + l31;

    for (int t = 0; t <= qb; ++t) {
        const int kv0 = t * 64;
        __syncthreads();
        // stage K tile [64 kv][128 d], XOR-swizzled source, linear LDS
        #pragma unroll
        for (int i = 0; i < 8; ++i) {
            int kv = wave * 32 + i * 4 + (lane >> 4);
            int slot = lane & 15;
            int sw = (slot & 8) | ((slot & 7) ^ (kv & 7));
            const u16* src = qkv + (long)(brow + kv0 + kv) * 6144 + 2048 +
                             h * 128 + sw * 8;
            gload_lds16(src, (char*)Ks_lds + (wave * 32 + i * 4) * 256);
        }
        // stage V^T tile [128 d][64 kv]
        #pragma unroll
        for (int i = 0; i < 8; ++i) {
            int d = wave * 64 + i * 8 + (lane >> 3);
            int slot = lane & 7;
            int sw = slot ^ (d & 7);
            const u16* src = vt + ((long)bh * 128 + d) * 2048 + kv0 + sw * 8;
            gload_lds16(src, (char*)Vt_lds + (wave * 64 + i * 8) * 128);
        }
        __syncthreads();
        if (t < qb)
            attn_tile<false>(kv0, qg, wave, l31, hi, Ks_lds, Vt_lds, qf, st);
        else
            attn_tile<true>(kv0, qg, wave, l31, hi, Ks_lds, Vt_lds, qf, st);
    }

    // epilogue: O^T[d][q] / l -> out[b, q, h*128+d]
    float inv = 1.0f / st.l_i;
    long orow = (long)(brow + q0 + wave * 32 + l31);
    #pragma unroll
    for (int dblk = 0; dblk < 4; ++dblk)
        #pragma unroll
        for (int rq = 0; rq < 4; ++rq) {
            u16x4 o4;
            #pragma unroll
            for (int m = 0; m < 4; ++m) o4[m] = f2b(st.acc[dblk][rq * 4 + m] * inv);
            int d = dblk * 32 + 8 * rq + 4 * hi;
            *(u16x4*)(out + orow * 2048 + h * 128 + d) = o4;
        }
}

// ---------------- launch --------------------------------------------------
extern "C" void kernel_launch(void* const* d_in, const int* in_sizes, int n_in,
                              void* d_out, int out_size, void* d_ws, size_t ws_size,
                              hipStream_t stream) {
    const float* x     = (const float*)d_in[0];
    const float* cosb  = (const float*)d_in[1];
    const float* sinb  = (const float*)d_in[2];
    const float* g1    = (const float*)d_in[3];
    const float* g2    = (const float*)d_in[4];
    const float* w_qkv = (const float*)d_in[5];
    const float* w_out = (const float*)d_in[6];
    const float* w_fc1 = (const float*)d_in[7];
    const float* w_fc2 = (const float*)d_in[8];

    char* ws = (char*)d_ws;
    u16* wqkv_b = (u16*)(ws);                    // 6144x2048 bf16
    u16* wout_b = (u16*)(ws + 25165824);         // 2048x2048
    u16* wfc1_b = (u16*)(ws + 33554432);         // 8192x2048
    u16* wfc2_b = (u16*)(ws + 67108864);         // 2048x8192
    u16* h_b    = (u16*)(ws + 100663296);        // 4096x2048 (h1 / vt / h2)
    u16* qkv_b  = (u16*)(ws + 117440512);        // 4096x6144
    u16* attn_b = (u16*)(ws + 167772160);        // 4096x2048
    u16* vt_b   = h_b;                           // 32x128x2048 (after qkv GEMM)
    u16* hg_b   = qkv_b;                         // 4096x8192, reuses qkv+attn
    float* xout = (float*)d_out;

    cvt_k<<<12288, 256, 0, stream>>>(w_qkv, wqkv_b, 12582912L);
    cvt_k<<<4096, 256, 0, stream>>>(w_out, wout_b, 4194304L);
    cvt_k<<<16384, 256, 0, stream>>>(w_fc1, wfc1_b, 16777216L);
    cvt_k<<<16384, 256, 0, stream>>>(w_fc2, wfc2_b, 16777216L);

    rmsnorm_k<<<4096, 256, 0, stream>>>(x, g1, h_b);
    gemm_bt<0><<<dim3(48, 32), 256, 0, stream>>>(h_b, wqkv_b, 4096, 6144, 2048,
                                                 qkv_b, nullptr, nullptr);
    rope_k<<<8192, 256, 0, stream>>>(qkv_b, cosb, sinb);
    vtrans_k<<<dim3(32, 32), 256, 0, stream>>>(qkv_b, vt_b);
    attn2_k<<<dim3(32, 32), 128, 0, stream>>>(qkv_b, vt_b, attn_b);
    gemm_bt<1><<<dim3(16, 32), 256, 0, stream>>>(attn_b, wout_b, 4096, 2048, 2048,
                                                 nullptr, xout, x);
    rmsnorm_k<<<4096, 256, 0, stream>>>(xout, g2, h_b);
    gemm_bt<2><<<dim3(64, 32), 256, 0, stream>>>(h_b, wfc1_b, 4096, 8192, 2048,
                                                 hg_b, nullptr, nullptr);
    gemm_bt<1><<<dim3(16, 32), 256, 0, stream>>>(hg_b, wfc2_b, 4096, 2048, 8192,
                                                 nullptr, xout, xout);
}

// Round 3
// 754.253 us; speedup vs baseline: 1.4675x; 1.1328x over previous
//
#include <hip/hip_runtime.h>
#include <stdint.h>

typedef unsigned short u16;
typedef u16 u16x4 __attribute__((ext_vector_type(4)));
typedef u16 u16x8 __attribute__((ext_vector_type(8)));
typedef __bf16 bf16x8 __attribute__((ext_vector_type(8)));
typedef float f32x4 __attribute__((ext_vector_type(4)));
typedef float f32x16 __attribute__((ext_vector_type(16)));

#define MFMA16 __builtin_amdgcn_mfma_f32_16x16x32_bf16
#define MFMA32 __builtin_amdgcn_mfma_f32_32x32x16_bf16

static __device__ __forceinline__ float b2f(u16 u) {
    union { unsigned int i; float f; } v; v.i = ((unsigned int)u) << 16; return v.f;
}
static __device__ __forceinline__ u16 f2b(float f) {
    union { float f; unsigned int i; } v; v.f = f;
    unsigned int r = (v.i + 0x7fffu + ((v.i >> 16) & 1u)) >> 16;
    return (u16)r;
}
static __device__ __forceinline__ unsigned pk2(float lo, float hi) {
    union { __bf16 b[2]; unsigned u; } t;
    t.b[0] = (__bf16)lo; t.b[1] = (__bf16)hi; return t.u;
}
static __device__ __forceinline__ void gload_lds16(const void* g, void* l) {
    __builtin_amdgcn_global_load_lds((__attribute__((address_space(1))) void*)g,
                                     (__attribute__((address_space(3))) void*)l,
                                     16, 0, 0);
}

// ---------------- fp32 -> bf16 weight conversion ----------------
__global__ __launch_bounds__(256) void cvt_k(const float* __restrict__ in,
                                             u16* __restrict__ out, long n) {
    long i = ((long)blockIdx.x * 256 + threadIdx.x) * 4;
    if (i >= n) return;
    float4 v = *(const float4*)(in + i);
    u16x4 o; o[0] = f2b(v.x); o[1] = f2b(v.y); o[2] = f2b(v.z); o[3] = f2b(v.w);
    *(u16x4*)(out + i) = o;
}

// ---------------- RMSNorm: fp32 in -> bf16 out (D=2048) ----------------------
__global__ __launch_bounds__(256) void rmsnorm_k(const float* __restrict__ x,
                                                 const float* __restrict__ g,
                                                 u16* __restrict__ out) {
    const long row = blockIdx.x;
    const int tid = threadIdx.x;
    const float* xr = x + row * 2048;
    float4 a = *(const float4*)(xr + tid * 4);
    float4 b = *(const float4*)(xr + 1024 + tid * 4);
    float ss = a.x*a.x + a.y*a.y + a.z*a.z + a.w*a.w
             + b.x*b.x + b.y*b.y + b.z*b.z + b.w*b.w;
    #pragma unroll
    for (int d = 1; d < 64; d <<= 1) ss += __shfl_xor(ss, d);
    __shared__ float red[4];
    if ((tid & 63) == 0) red[tid >> 6] = ss;
    __syncthreads();
    float tot = red[0] + red[1] + red[2] + red[3];
    float rinv = rsqrtf(tot * (1.0f / 2048.0f) + 1e-6f);
    float4 g0 = *(const float4*)(g + tid * 4);
    float4 g1 = *(const float4*)(g + 1024 + tid * 4);
    u16x4 o0, o1;
    o0[0] = f2b(a.x * g0.x * rinv); o0[1] = f2b(a.y * g0.y * rinv);
    o0[2] = f2b(a.z * g0.z * rinv); o0[3] = f2b(a.w * g0.w * rinv);
    o1[0] = f2b(b.x * g1.x * rinv); o1[1] = f2b(b.y * g1.y * rinv);
    o1[2] = f2b(b.z * g1.z * rinv); o1[3] = f2b(b.w * g1.w * rinv);
    *(u16x4*)(out + row * 2048 + tid * 4) = o0;
    *(u16x4*)(out + row * 2048 + 1024 + tid * 4) = o1;
}

// ---------------- RoPE in-place on bf16 qkv; q additionally scaled ------------
__global__ __launch_bounds__(256) void rope_k(u16* __restrict__ qkv,
                                              const float* __restrict__ cosb,
                                              const float* __restrict__ sinb) {
    long idx = (long)blockIdx.x * 256 + threadIdx.x;
    int d = (int)(idx & 15) * 4;
    int h = (int)((idx >> 4) & 15);
    int which = (int)((idx >> 8) & 1);
    long row = idx >> 9;
    int s = (int)(row & 2047);
    u16* base = qkv + row * 6144 + which * 2048 + h * 128;
    u16x4 ua = *(u16x4*)(base + d);
    u16x4 ub = *(u16x4*)(base + d + 64);
    float4 c4 = *(const float4*)(cosb + (long)s * 128 + d);
    float4 s4 = *(const float4*)(sinb + (long)s * 128 + d);
    float cc[4] = {c4.x, c4.y, c4.z, c4.w};
    float sn[4] = {s4.x, s4.y, s4.z, s4.w};
    float scale = (which == 0) ? 0.08838834764831845f : 1.0f;
    u16x4 oa, ob;
    #pragma unroll
    for (int j = 0; j < 4; ++j) {
        float a = b2f(ua[j]), b = b2f(ub[j]);
        oa[j] = f2b((a * cc[j] - b * sn[j]) * scale);
        ob[j] = f2b((b * cc[j] + a * sn[j]) * scale);
    }
    *(u16x4*)(base + d) = oa;
    *(u16x4*)(base + d + 64) = ob;
}

// ---------------- V transpose: qkv V section -> vt[bh][d][s] -----------------
__global__ __launch_bounds__(256) void vtrans_k(const u16* __restrict__ qkv,
                                                u16* __restrict__ vt) {
    __shared__ u16 t[128 * 65];
    const int bh = blockIdx.y, b = bh >> 4, h = bh & 15;
    const int s0 = blockIdx.x * 64;
    const int tid = threadIdx.x;
    #pragma unroll
    for (int it = 0; it < 4; ++it) {
        int flat = it * 256 + tid;
        int sl = flat >> 4, slot = flat & 15;
        u16x8 v = *(const u16x8*)(qkv + (long)(b * 2048 + s0 + sl) * 6144 + 4096 +
                                  h * 128 + slot * 8);
        #pragma unroll
        for (int j = 0; j < 8; ++j) t[(slot * 8 + j) * 65 + sl] = v[j];
    }
    __syncthreads();
    #pragma unroll
    for (int it = 0; it < 4; ++it) {
        int flat = it * 256 + tid;
        int d = flat >> 3, sg = flat & 7;
        u16x8 v;
        #pragma unroll
        for (int j = 0; j < 8; ++j) v[j] = t[d * 65 + sg * 8 + j];
        *(u16x8*)(vt + ((long)bh * 128 + d) * 2048 + s0 + sg * 8) = v;
    }
}

// ---------------- GEMM 128x128 (m97 structure), kept for out-proj ------------
template <int EPI>
__global__ __launch_bounds__(256) void gemm_bt(const u16* __restrict__ A,
                                               const u16* __restrict__ W,
                                               int M, int N, int K,
                                               u16* outb, float* outf,
                                               const float* res) {
    __shared__ u16 As[128 * 32];
    __shared__ u16 Bs[128 * 32];
    const int tid = threadIdx.x;
    const int wave = tid >> 6, lane = tid & 63;
    const int wr = wave >> 1, wc = wave & 1;
    const int bm = blockIdx.y, bn = blockIdx.x;
    const int l4 = lane >> 2;
    const int c8 = (lane & 3) * 8;
    const long arow0 = (long)bm * 128;
    const long brow0 = (long)bn * 128;

    f32x4 acc[4][4];
    #pragma unroll
    for (int m = 0; m < 4; ++m)
        #pragma unroll
        for (int n = 0; n < 4; ++n) acc[m][n] = (f32x4){0.f, 0.f, 0.f, 0.f};

    const int nk = K >> 5;
    for (int kt = 0; kt < nk; ++kt) {
        __syncthreads();
        #pragma unroll
        for (int p = 0; p < 2; ++p) {
            int row = p * 64 + wave * 16 + l4;
            const u16* ga = A + (arow0 + row) * (long)K + kt * 32 + c8;
            gload_lds16(ga, (char*)As + p * 4096 + wave * 1024);
            const u16* gb = W + (brow0 + row) * (long)K + kt * 32 + c8;
            gload_lds16(gb, (char*)Bs + p * 4096 + wave * 1024);
        }
        __syncthreads();
        bf16x8 af[4], bfr[4];
        #pragma unroll
        for (int m = 0; m < 4; ++m)
            af[m] = *(const bf16x8*)((const char*)As +
                     (wr * 64 + m * 16 + (lane & 15)) * 64 + (lane >> 4) * 16);
        #pragma unroll
        for (int n = 0; n < 4; ++n)
            bfr[n] = *(const bf16x8*)((const char*)Bs +
                     (wc * 64 + n * 16 + (lane & 15)) * 64 + (lane >> 4) * 16);
        #pragma unroll
        for (int m = 0; m < 4; ++m)
            #pragma unroll
            for (int n = 0; n < 4; ++n)
                acc[m][n] = MFMA16(af[m], bfr[n], acc[m][n], 0, 0, 0);
    }

    const int rb = bm * 128 + wr * 64 + ((lane >> 4) << 2);
    const int cb = bn * 128 + wc * 64 + (lane & 15);
    #pragma unroll
    for (int m = 0; m < 4; ++m) {
        #pragma unroll
        for (int r = 0; r < 4; ++r) {
            long row = rb + m * 16 + r;
            #pragma unroll
            for (int n = 0; n < 4; ++n) {
                long col = cb + n * 16;
                float v = acc[m][n][r];
                if (EPI == 1) {
                    outf[row * N + col] = res[row * N + col] + v;
                } else if (EPI == 2) {
                    float u = 0.7978845608028654f * v * (1.0f + 0.044715f * v * v);
                    float e = __expf(2.0f * u);
                    float t = 1.0f - 2.0f / (e + 1.0f);
                    outb[row * N + col] = f2b(0.5f * v * (1.0f + t));
                } else {
                    outb[row * N + col] = f2b(v);
                }
            }
        }
    }
}

// ---------------- GEMM 256x256, 8-phase counted-vmcnt pipeline ---------------
// 512 thr = 8 waves (2M x 4N), BK=64, LDS = 2 buf x (A 256x64 + B 256x64) bf16
// stored as 16x32 swizzled subtiles (1024B each = one wave gload_lds).
// Swizzle: col_chunk ^= ((row>>3)&1)<<4 (elements), applied on global source
// at staging AND on ds_read (both-sides, rule 21).
// Phase = {4/8 ds_read_b128 | stage one quarter freed last phase | barrier |
//          setprio 16xMFMA | barrier}; vmcnt(6) only at phases 4/8.
#define DS_A(BUF, SM, KK) (*(const bf16x8*)(ldsb + (BUF)*32768 + \
        ((((SM)*2) + (KK)) << 10) + rin64 + cst2))
#define DS_B(BUF, SN, KK) (*(const bf16x8*)(ldsb + 65536 + (BUF)*32768 + \
        ((((SN)*2) + (KK)) << 10) + rin64 + cst2))
#define STAGE_A(BUF, SK, KT) do { \
    gload_lds16(sA0 + ((long)(KT)*64 + (SK)*32), ldsb + (BUF)*32768 + (w4 + (SK))*1024); \
    gload_lds16(sA1 + ((long)(KT)*64 + (SK)*32), ldsb + (BUF)*32768 + (w4 + 2 + (SK))*1024); \
} while (0)
#define STAGE_B(BUF, SK, KT) do { \
    gload_lds16(sB0 + ((long)(KT)*64 + (SK)*32), ldsb + 65536 + (BUF)*32768 + (w4 + (SK))*1024); \
    gload_lds16(sB1 + ((long)(KT)*64 + (SK)*32), ldsb + 65536 + (BUF)*32768 + (w4 + 2 + (SK))*1024); \
} while (0)
#define PHASE(BUF, MH, KK, RDB, STAGE_STMT, VM) do { \
    bf16x8 af[4]; \
    _Pragma("unroll") \
    for (int m = 0; m < 4; ++m) af[m] = DS_A(BUF, wr8 + (MH)*4 + m, KK); \
    if (RDB) { \
        bfr[0] = DS_B(BUF, wc4 + 0, KK); bfr[1] = DS_B(BUF, wc4 + 1, KK); \
        bfr[2] = DS_B(BUF, wc4 + 2, KK); bfr[3] = DS_B(BUF, wc4 + 3, KK); \
    } \
    STAGE_STMT; \
    if (VM) { asm volatile("s_waitcnt vmcnt(6)" ::: "memory"); } \
    __builtin_amdgcn_sched_barrier(0); \
    __builtin_amdgcn_s_barrier(); \
    __builtin_amdgcn_sched_barrier(0); \
    __builtin_amdgcn_s_setprio(1); \
    _Pragma("unroll") \
    for (int m = 0; m < 4; ++m) \
        _Pragma("unroll") \
        for (int n = 0; n < 4; ++n) \
            acc[(MH)*4 + m][n] = MFMA16(af[m], bfr[n], acc[(MH)*4 + m][n], 0, 0, 0); \
    __builtin_amdgcn_s_setprio(0); \
    __builtin_amdgcn_sched_barrier(0); \
    __builtin_amdgcn_s_barrier(); \
    __builtin_amdgcn_sched_barrier(0); \
} while (0)

template <int EPI>
__global__ __launch_bounds__(512, 2) void gemm256(const u16* __restrict__ A,
                                                  const u16* __restrict__ W,
                                                  int M, int N, int K,
                                                  u16* outb, float* outf,
                                                  const float* res) {
    __shared__ u16 lds_[65536];
    char* ldsb = (char*)lds_;
    const int tid = threadIdx.x;
    const int w = tid >> 6, l = tid & 63;
    const int w4 = w * 4;
    const int wr8 = (w >> 2) * 8;      // A subtile base (wave M-half)
    const int wc4 = (w & 3) * 4;       // B subtile base (wave N-quarter)
    const int rin64 = (l & 15) * 64;
    const int cst2 = ((((l >> 4) * 8) ^ (((l >> 3) & 1) << 4)) << 1);

    // XCD-aware bijective swizzle (nwg % 8 == 0 for all our shapes)
    const int nbn = N >> 8;
    const int nwg = gridDim.x;
    const int cpx = nwg >> 3;
    const int bid = blockIdx.x;
    const int wg = (bid & 7) * cpx + (bid >> 3);
    const int bm = wg / nbn, bn = wg % nbn;

    // staging source pointers: lane l covers subtile row r4=l>>2, chunk (l&3)*8
    const int r4 = l >> 2;
    const int clog = ((l & 3) * 8) ^ (((r4 >> 3) & 1) << 4);
    const u16* sA0 = A + ((long)bm * 256 + (w * 2 + 0) * 16 + r4) * K + clog;
    const u16* sA1 = A + ((long)bm * 256 + (w * 2 + 1) * 16 + r4) * K + clog;
    const u16* sB0 = W + ((long)bn * 256 + (w * 2 + 0) * 16 + r4) * K + clog;
    const u16* sB1 = W + ((long)bn * 256 + (w * 2 + 1) * 16 + r4) * K + clog;

    f32x4 acc[8][4];
    #pragma unroll
    for (int m = 0; m < 8; ++m)
        #pragma unroll
        for (int n = 0; n < 4; ++n) acc[m][n] = (f32x4){0.f, 0.f, 0.f, 0.f};
    bf16x8 bfr[4];

    const int nkt = K >> 6;
    const int niter = nkt >> 1;

    // prologue: tile0 full into buf0; tile1 {B0,A0,B1} into buf1
    STAGE_B(0, 0, 0); STAGE_A(0, 0, 0); STAGE_B(0, 1, 0); STAGE_A(0, 1, 0);
    STAGE_B(1, 0, 1); STAGE_A(1, 0, 1); STAGE_B(1, 1, 1);
    asm volatile("s_waitcnt vmcnt(6)" ::: "memory");
    __builtin_amdgcn_sched_barrier(0);
    __builtin_amdgcn_s_barrier();
    __builtin_amdgcn_sched_barrier(0);

    for (int it = 0; it < niter; ++it) {
        const int t = it * 2;
        const int t1 = t + 1;
        const int t2 = (t + 2 < nkt) ? t + 2 : nkt - 1;
        const int t3 = (t + 3 < nkt) ? t + 3 : nkt - 1;
        PHASE(0, 0, 0, 1, STAGE_A(1, 1, t1), 0);
        PHASE(0, 1, 0, 0, STAGE_B(0, 0, t2), 0);
        PHASE(0, 0, 1, 1, STAGE_A(0, 0, t2), 0);
        PHASE(0, 1, 1, 0, STAGE_B(0, 1, t2), 1);
        PHASE(1, 0, 0, 1, STAGE_A(0, 1, t2), 0);
        PHASE(1, 1, 0, 0, STAGE_B(1, 0, t3), 0);
        PHASE(1, 0, 1, 1, STAGE_A(1, 0, t3), 0);
        PHASE(1, 1, 1, 0, STAGE_B(1, 1, t3), 1);
    }
    asm volatile("s_waitcnt vmcnt(0)" ::: "memory");

    // epilogue
    const int rb = bm * 256 + (wr8 >> 3) * 128 + ((l >> 4) << 2);
    const int cb = bn * 256 + (w & 3) * 64 + (l & 15);
    #pragma unroll
    for (int m = 0; m < 8; ++m) {
        #pragma unroll
        for (int r = 0; r < 4; ++r) {
            long row = rb + m * 16 + r;
            #pragma unroll
            for (int n = 0; n < 4; ++n) {
                long col = cb + n * 16;
                float v = acc[m][n][r];
                if (EPI == 1) {
                    outf[row * N + col] = res[row * N + col] + v;
                } else if (EPI == 2) {
                    float u = 0.7978845608028654f * v * (1.0f + 0.044715f * v * v);
                    float e = __expf(2.0f * u);
                    float tgl = 1.0f - 2.0f / (e + 1.0f);
                    outb[row * N + col] = f2b(0.5f * v * (1.0f + tgl));
                } else {
                    outb[row * N + col] = f2b(v);
                }
            }
        }
    }
}

// ---------------- causal flash attention v2 ----------------------------------
struct AttnState {
    f32x16 acc[4];
    float m_i, l_i;
};

template <bool DIAG>
static __device__ __forceinline__ void attn_tile(
    int kv0, int qg, int wave, int l31, int hi,
    const u16* __restrict__ Ks, const u16* __restrict__ Vt,
    const bf16x8 (&qf)[8], AttnState& st)
{
    const bool do_g1 = !(DIAG && wave == 0);
    f32x16 sacc0, sacc1;
    #pragma unroll
    for (int r = 0; r < 16; ++r) { sacc0[r] = 0.f; sacc1[r] = 0.f; }

    #pragma unroll
    for (int dsl = 0; dsl < 8; ++dsl) {
        int slot = dsl * 2 + hi;
        int kv = l31;
        int sw = (slot & 8) | ((slot & 7) ^ (kv & 7));
        bf16x8 kf = *(const bf16x8*)(Ks + kv * 128 + sw * 8);
        sacc0 = MFMA32(kf, qf[dsl], sacc0, 0, 0, 0);
    }
    if (do_g1) {
        #pragma unroll
        for (int dsl = 0; dsl < 8; ++dsl) {
            int slot = dsl * 2 + hi;
            int kv = 32 + l31;
            int sw = (slot & 8) | ((slot & 7) ^ (kv & 7));
            bf16x8 kf = *(const bf16x8*)(Ks + kv * 128 + sw * 8);
            sacc1 = MFMA32(kf, qf[dsl], sacc1, 0, 0, 0);
        }
    }

    float sv[2][16];
    #pragma unroll
    for (int r = 0; r < 16; ++r) {
        sv[0][r] = sacc0[r];
        sv[1][r] = do_g1 ? sacc1[r] : -INFINITY;
    }
    if (DIAG) {
        #pragma unroll
        for (int g = 0; g < 2; ++g)
            #pragma unroll
            for (int r = 0; r < 16; ++r) {
                int kvg = kv0 + g * 32 + ((r & 3) + 8 * (r >> 2) + 4 * hi);
                if (kvg > qg) sv[g][r] = -INFINITY;
            }
    }

    float mx = sv[0][0];
    #pragma unroll
    for (int r = 1; r < 16; ++r) mx = fmaxf(mx, sv[0][r]);
    #pragma unroll
    for (int r = 0; r < 16; ++r) mx = fmaxf(mx, sv[1][r]);
    mx = fmaxf(mx, __shfl_xor(mx, 32));

    bool defer = __all(mx <= st.m_i + 8.0f);
    if (!defer) {
        float mnew = fmaxf(st.m_i, mx);
        float f = __expf(st.m_i - mnew);
        st.l_i *= f;
        #pragma unroll
        for (int dblk = 0; dblk < 4; ++dblk)
            #pragma unroll
            for (int r = 0; r < 16; ++r) st.acc[dblk][r] *= f;
        st.m_i = mnew;
    }

    float ssum = 0.f;
    #pragma unroll
    for (int g = 0; g < 2; ++g)
        #pragma unroll
        for (int r = 0; r < 16; ++r) {
            float e = __expf(sv[g][r] - st.m_i);
            sv[g][r] = e;
            ssum += e;
        }
    ssum += __shfl_xor(ssum, 32);
    st.l_i += ssum;

    unsigned w[2][4][2];
    #pragma unroll
    for (int g = 0; g < 2; ++g)
        #pragma unroll
        for (int q4 = 0; q4 < 4; ++q4) {
            w[g][q4][0] = pk2(sv[g][4 * q4 + 0], sv[g][4 * q4 + 1]);
            w[g][q4][1] = pk2(sv[g][4 * q4 + 2], sv[g][4 * q4 + 3]);
        }
    bf16x8 pfrag[4];
    #pragma unroll
    for (int ks = 0; ks < 4; ++ks) {
        int g = ks >> 1, h2 = ks & 1;
        unsigned o0 = hi ? w[g][2 * h2 + 1][0] : w[g][2 * h2][0];
        unsigned o1 = hi ? w[g][2 * h2 + 1][1] : w[g][2 * h2][1];
        unsigned t0 = hi ? w[g][2 * h2][0] : w[g][2 * h2 + 1][0];
        unsigned t1 = hi ? w[g][2 * h2][1] : w[g][2 * h2 + 1][1];
        unsigned s0v = __shfl_xor(t0, 32);
        unsigned s1v = __shfl_xor(t1, 32);
        union { unsigned u[4]; bf16x8 v; } cv;
        cv.u[0] = hi ? s0v : o0;
        cv.u[1] = hi ? s1v : o1;
        cv.u[2] = hi ? o0 : s0v;
        cv.u[3] = hi ? o1 : s1v;
        pfrag[ks] = cv.v;
    }

    #pragma unroll
    for (int dblk = 0; dblk < 4; ++dblk) {
        int d = dblk * 32 + l31;
        #pragma unroll
        for (int ks = 0; ks < 4; ++ks) {
            if (ks >= 2 && !do_g1) continue;
            int slot = ks * 2 + hi;
            bf16x8 vf = *(const bf16x8*)(Vt + d * 64 + (slot ^ (d & 7)) * 8);
            st.acc[dblk] = MFMA32(vf, pfrag[ks], st.acc[dblk], 0, 0, 0);
        }
    }
}

__global__ __launch_bounds__(128) void attn2_k(const u16* __restrict__ qkv,
                                               const u16* __restrict__ vt,
                                               u16* __restrict__ out) {
    const int bh = blockIdx.y;
    const int b = bh >> 4, h = bh & 15;
    const int qb = blockIdx.x;
    const int q0 = qb * 64;
    const int tid = threadIdx.x, wave = tid >> 6, lane = tid & 63;
    const int l31 = lane & 31, hi = lane >> 5;
    const int brow = b * 2048;
    __shared__ u16 Ks_lds[64 * 128];
    __shared__ u16 Vt_lds[128 * 64];

    bf16x8 qf[8];
    {
        const u16* qp = qkv + (long)(brow + q0 + wave * 32 + l31) * 6144 +
                        h * 128 + hi * 8;
        #pragma unroll
        for (int dsl = 0; dsl < 8; ++dsl) qf[dsl] = *(const bf16x8*)(qp + dsl * 16);
    }

    AttnState st;
    st.m_i = -INFINITY; st.l_i = 0.f;
    #pragma unroll
    for (int dblk = 0; dblk < 4; ++dblk)
        #pragma unroll
        for (int r = 0; r < 16; ++r) st.acc[dblk][r] = 0.f;

    const int qg = q0 + wave * 32 + l31;

    for (int t = 0; t <= qb; ++t) {
        const int kv0 = t * 64;
        __syncthreads();
        #pragma unroll
        for (int i = 0; i < 8; ++i) {
            int kv = wave * 32 + i * 4 + (lane >> 4);
            int slot = lane & 15;
            int sw = (slot & 8) | ((slot & 7) ^ (kv & 7));
            const u16* src = qkv + (long)(brow + kv0 + kv) * 6144 + 2048 +
                             h * 128 + sw * 8;
            gload_lds16(src, (char*)Ks_lds + (wave * 32 + i * 4) * 256);
        }
        #pragma unroll
        for (int i = 0; i < 8; ++i) {
            int d = wave * 64 + i * 8 + (lane >> 3);
            int slot = lane & 7;
            int sw = slot ^ (d & 7);
            const u16* src = vt + ((long)bh * 128 + d) * 2048 + kv0 + sw * 8;
            gload_lds16(src, (char*)Vt_lds + (wave * 64 + i * 8) * 128);
        }
        __syncthreads();
        if (t < qb)
            attn_tile<false>(kv0, qg, wave, l31, hi, Ks_lds, Vt_lds, qf, st);
        else
            attn_tile<true>(kv0, qg, wave, l31, hi, Ks_lds, Vt_lds, qf, st);
    }

    float inv = 1.0f / st.l_i;
    long orow = (long)(brow + q0 + wave * 32 + l31);
    #pragma unroll
    for (int dblk = 0; dblk < 4; ++dblk)
        #pragma unroll
        for (int rq = 0; rq < 4; ++rq) {
            u16x4 o4;
            #pragma unroll
            for (int m = 0; m < 4; ++m) o4[m] = f2b(st.acc[dblk][rq * 4 + m] * inv);
            int d = dblk * 32 + 8 * rq + 4 * hi;
            *(u16x4*)(out + orow * 2048 + h * 128 + d) = o4;
        }
}

// ---------------- launch --------------------------------------------------
extern "C" void kernel_launch(void* const* d_in, const int* in_sizes, int n_in,
                              void* d_out, int out_size, void* d_ws, size_t ws_size,
                              hipStream_t stream) {
    const float* x     = (const float*)d_in[0];
    const float* cosb  = (const float*)d_in[1];
    const float* sinb  = (const float*)d_in[2];
    const float* g1    = (const float*)d_in[3];
    const float* g2    = (const float*)d_in[4];
    const float* w_qkv = (const float*)d_in[5];
    const float* w_out = (const float*)d_in[6];
    const float* w_fc1 = (const float*)d_in[7];
    const float* w_fc2 = (const float*)d_in[8];

    char* ws = (char*)d_ws;
    u16* wqkv_b = (u16*)(ws);                    // 6144x2048 bf16
    u16* wout_b = (u16*)(ws + 25165824);         // 2048x2048
    u16* wfc1_b = (u16*)(ws + 33554432);         // 8192x2048
    u16* wfc2_b = (u16*)(ws + 67108864);         // 2048x8192
    u16* h_b    = (u16*)(ws + 100663296);        // 4096x2048 (h1 / vt / h2)
    u16* qkv_b  = (u16*)(ws + 117440512);        // 4096x6144
    u16* attn_b = (u16*)(ws + 167772160);        // 4096x2048
    u16* vt_b   = h_b;                           // 32x128x2048 (after qkv GEMM)
    u16* hg_b   = qkv_b;                         // 4096x8192, reuses qkv+attn
    float* xout = (float*)d_out;

    cvt_k<<<12288, 256, 0, stream>>>(w_qkv, wqkv_b, 12582912L);
    cvt_k<<<4096, 256, 0, stream>>>(w_out, wout_b, 4194304L);
    cvt_k<<<16384, 256, 0, stream>>>(w_fc1, wfc1_b, 16777216L);
    cvt_k<<<16384, 256, 0, stream>>>(w_fc2, wfc2_b, 16777216L);

    rmsnorm_k<<<4096, 256, 0, stream>>>(x, g1, h_b);
    gemm256<0><<<384, 512, 0, stream>>>(h_b, wqkv_b, 4096, 6144, 2048,
                                        qkv_b, nullptr, nullptr);
    rope_k<<<8192, 256, 0, stream>>>(qkv_b, cosb, sinb);
    vtrans_k<<<dim3(32, 32), 256, 0, stream>>>(qkv_b, vt_b);
    attn2_k<<<dim3(32, 32), 128, 0, stream>>>(qkv_b, vt_b, attn_b);
    gemm_bt<1><<<dim3(16, 32), 256, 0, stream>>>(attn_b, wout_b, 4096, 2048, 2048,
                                                 nullptr, xout, x);
    rmsnorm_k<<<4096, 256, 0, stream>>>(xout, g2, h_b);
    gemm256<2><<<512, 512, 0, stream>>>(h_b, wfc1_b, 4096, 8192, 2048,
                                        hg_b, nullptr, nullptr);
    gemm256<1><<<128, 512, 0, stream>>>(hg_b, wfc2_b, 4096, 2048, 8192,
                                        nullptr, xout, xout);
}

// Round 4
// 686.685 us; speedup vs baseline: 1.6118x; 1.0984x over previous
//
#include <hip/hip_runtime.h>
#include <stdint.h>

typedef unsigned short u16;
typedef u16 u16x4 __attribute__((ext_vector_type(4)));
typedef u16 u16x8 __attribute__((ext_vector_type(8)));
typedef __bf16 bf16x8 __attribute__((ext_vector_type(8)));
typedef float f32x4 __attribute__((ext_vector_type(4)));
typedef float f32x16 __attribute__((ext_vector_type(16)));

#define MFMA16 __builtin_amdgcn_mfma_f32_16x16x32_bf16
#define MFMA32 __builtin_amdgcn_mfma_f32_32x32x16_bf16

static __device__ __forceinline__ float b2f(u16 u) {
    union { unsigned int i; float f; } v; v.i = ((unsigned int)u) << 16; return v.f;
}
static __device__ __forceinline__ u16 f2b(float f) {
    union { float f; unsigned int i; } v; v.f = f;
    unsigned int r = (v.i + 0x7fffu + ((v.i >> 16) & 1u)) >> 16;
    return (u16)r;
}
static __device__ __forceinline__ unsigned pk2(float lo, float hi) {
    union { __bf16 b[2]; unsigned u; } t;
    t.b[0] = (__bf16)lo; t.b[1] = (__bf16)hi; return t.u;
}
static __device__ __forceinline__ void gload_lds16(const void* g, void* l) {
    __builtin_amdgcn_global_load_lds((__attribute__((address_space(1))) void*)g,
                                     (__attribute__((address_space(3))) void*)l,
                                     16, 0, 0);
}

// ---------------- fp32 -> bf16 weight conversion ----------------
__global__ __launch_bounds__(256) void cvt_k(const float* __restrict__ in,
                                             u16* __restrict__ out, long n) {
    long i = ((long)blockIdx.x * 256 + threadIdx.x) * 4;
    if (i >= n) return;
    float4 v = *(const float4*)(in + i);
    u16x4 o; o[0] = f2b(v.x); o[1] = f2b(v.y); o[2] = f2b(v.z); o[3] = f2b(v.w);
    *(u16x4*)(out + i) = o;
}

// ---------------- fused split-K reduce: xout += p0 + p1 ----------------------
__global__ __launch_bounds__(256) void addred_k(float* __restrict__ xout,
                                                const float* __restrict__ p0,
                                                const float* __restrict__ p1) {
    long i = ((long)blockIdx.x * 256 + threadIdx.x) * 4;
    float4 a = *(const float4*)(xout + i);
    float4 b = *(const float4*)(p0 + i);
    float4 c = *(const float4*)(p1 + i);
    a.x += b.x + c.x; a.y += b.y + c.y; a.z += b.z + c.z; a.w += b.w + c.w;
    *(float4*)(xout + i) = a;
}

// ---------------- RMSNorm: fp32 in -> bf16 out (D=2048) ----------------------
__global__ __launch_bounds__(256) void rmsnorm_k(const float* __restrict__ x,
                                                 const float* __restrict__ g,
                                                 u16* __restrict__ out) {
    const long row = blockIdx.x;
    const int tid = threadIdx.x;
    const float* xr = x + row * 2048;
    float4 a = *(const float4*)(xr + tid * 4);
    float4 b = *(const float4*)(xr + 1024 + tid * 4);
    float ss = a.x*a.x + a.y*a.y + a.z*a.z + a.w*a.w
             + b.x*b.x + b.y*b.y + b.z*b.z + b.w*b.w;
    #pragma unroll
    for (int d = 1; d < 64; d <<= 1) ss += __shfl_xor(ss, d);
    __shared__ float red[4];
    if ((tid & 63) == 0) red[tid >> 6] = ss;
    __syncthreads();
    float tot = red[0] + red[1] + red[2] + red[3];
    float rinv = rsqrtf(tot * (1.0f / 2048.0f) + 1e-6f);
    float4 g0 = *(const float4*)(g + tid * 4);
    float4 g1 = *(const float4*)(g + 1024 + tid * 4);
    u16x4 o0, o1;
    o0[0] = f2b(a.x * g0.x * rinv); o0[1] = f2b(a.y * g0.y * rinv);
    o0[2] = f2b(a.z * g0.z * rinv); o0[3] = f2b(a.w * g0.w * rinv);
    o1[0] = f2b(b.x * g1.x * rinv); o1[1] = f2b(b.y * g1.y * rinv);
    o1[2] = f2b(b.z * g1.z * rinv); o1[3] = f2b(b.w * g1.w * rinv);
    *(u16x4*)(out + row * 2048 + tid * 4) = o0;
    *(u16x4*)(out + row * 2048 + 1024 + tid * 4) = o1;
}

// ---------------- RoPE in-place on bf16 qkv; q additionally scaled ------------
__global__ __launch_bounds__(256) void rope_k(u16* __restrict__ qkv,
                                              const float* __restrict__ cosb,
                                              const float* __restrict__ sinb) {
    long idx = (long)blockIdx.x * 256 + threadIdx.x;
    int d = (int)(idx & 15) * 4;
    int h = (int)((idx >> 4) & 15);
    int which = (int)((idx >> 8) & 1);
    long row = idx >> 9;
    int s = (int)(row & 2047);
    u16* base = qkv + row * 6144 + which * 2048 + h * 128;
    u16x4 ua = *(u16x4*)(base + d);
    u16x4 ub = *(u16x4*)(base + d + 64);
    float4 c4 = *(const float4*)(cosb + (long)s * 128 + d);
    float4 s4 = *(const float4*)(sinb + (long)s * 128 + d);
    float cc[4] = {c4.x, c4.y, c4.z, c4.w};
    float sn[4] = {s4.x, s4.y, s4.z, s4.w};
    float scale = (which == 0) ? 0.08838834764831845f : 1.0f;
    u16x4 oa, ob;
    #pragma unroll
    for (int j = 0; j < 4; ++j) {
        float a = b2f(ua[j]), b = b2f(ub[j]);
        oa[j] = f2b((a * cc[j] - b * sn[j]) * scale);
        ob[j] = f2b((b * cc[j] + a * sn[j]) * scale);
    }
    *(u16x4*)(base + d) = oa;
    *(u16x4*)(base + d + 64) = ob;
}

// ---------------- V transpose: qkv V section -> vt[bh][d][s] -----------------
__global__ __launch_bounds__(256) void vtrans_k(const u16* __restrict__ qkv,
                                                u16* __restrict__ vt) {
    __shared__ u16 t[128 * 65];
    const int bh = blockIdx.y, b = bh >> 4, h = bh & 15;
    const int s0 = blockIdx.x * 64;
    const int tid = threadIdx.x;
    #pragma unroll
    for (int it = 0; it < 4; ++it) {
        int flat = it * 256 + tid;
        int sl = flat >> 4, slot = flat & 15;
        u16x8 v = *(const u16x8*)(qkv + (long)(b * 2048 + s0 + sl) * 6144 + 4096 +
                                  h * 128 + slot * 8);
        #pragma unroll
        for (int j = 0; j < 8; ++j) t[(slot * 8 + j) * 65 + sl] = v[j];
    }
    __syncthreads();
    #pragma unroll
    for (int it = 0; it < 4; ++it) {
        int flat = it * 256 + tid;
        int d = flat >> 3, sg = flat & 7;
        u16x8 v;
        #pragma unroll
        for (int j = 0; j < 8; ++j) v[j] = t[d * 65 + sg * 8 + j];
        *(u16x8*)(vt + ((long)bh * 128 + d) * 2048 + s0 + sg * 8) = v;
    }
}

// ---------------- GEMM 128x128 (m97 structure), kept for out-proj ------------
template <int EPI>
__global__ __launch_bounds__(256) void gemm_bt(const u16* __restrict__ A,
                                               const u16* __restrict__ W,
                                               int M, int N, int K,
                                               u16* outb, float* outf,
                                               const float* res) {
    __shared__ u16 As[128 * 32];
    __shared__ u16 Bs[128 * 32];
    const int tid = threadIdx.x;
    const int wave = tid >> 6, lane = tid & 63;
    const int wr = wave >> 1, wc = wave & 1;
    const int bm = blockIdx.y, bn = blockIdx.x;
    const int l4 = lane >> 2;
    const int c8 = (lane & 3) * 8;
    const long arow0 = (long)bm * 128;
    const long brow0 = (long)bn * 128;

    f32x4 acc[4][4];
    #pragma unroll
    for (int m = 0; m < 4; ++m)
        #pragma unroll
        for (int n = 0; n < 4; ++n) acc[m][n] = (f32x4){0.f, 0.f, 0.f, 0.f};

    const int nk = K >> 5;
    for (int kt = 0; kt < nk; ++kt) {
        __syncthreads();
        #pragma unroll
        for (int p = 0; p < 2; ++p) {
            int row = p * 64 + wave * 16 + l4;
            const u16* ga = A + (arow0 + row) * (long)K + kt * 32 + c8;
            gload_lds16(ga, (char*)As + p * 4096 + wave * 1024);
            const u16* gb = W + (brow0 + row) * (long)K + kt * 32 + c8;
            gload_lds16(gb, (char*)Bs + p * 4096 + wave * 1024);
        }
        __syncthreads();
        bf16x8 af[4], bfr[4];
        #pragma unroll
        for (int m = 0; m < 4; ++m)
            af[m] = *(const bf16x8*)((const char*)As +
                     (wr * 64 + m * 16 + (lane & 15)) * 64 + (lane >> 4) * 16);
        #pragma unroll
        for (int n = 0; n < 4; ++n)
            bfr[n] = *(const bf16x8*)((const char*)Bs +
                     (wc * 64 + n * 16 + (lane & 15)) * 64 + (lane >> 4) * 16);
        #pragma unroll
        for (int m = 0; m < 4; ++m)
            #pragma unroll
            for (int n = 0; n < 4; ++n)
                acc[m][n] = MFMA16(af[m], bfr[n], acc[m][n], 0, 0, 0);
    }

    const int rb = bm * 128 + wr * 64 + ((lane >> 4) << 2);
    const int cb = bn * 128 + wc * 64 + (lane & 15);
    #pragma unroll
    for (int m = 0; m < 4; ++m) {
        #pragma unroll
        for (int r = 0; r < 4; ++r) {
            long row = rb + m * 16 + r;
            #pragma unroll
            for (int n = 0; n < 4; ++n) {
                long col = cb + n * 16;
                float v = acc[m][n][r];
                if (EPI == 1) {
                    outf[row * N + col] = res[row * N + col] + v;
                } else if (EPI == 2) {
                    float u = 0.7978845608028654f * v * (1.0f + 0.044715f * v * v);
                    float e = __expf(2.0f * u);
                    float t = 1.0f - 2.0f / (e + 1.0f);
                    outb[row * N + col] = f2b(0.5f * v * (1.0f + t));
                } else {
                    outb[row * N + col] = f2b(v);
                }
            }
        }
    }
}

// ---------------- GEMM 256x256, 8-phase counted-vmcnt pipeline ---------------
// 512 thr = 8 waves (2M x 4N), BK=64, LDS = 2 buf x (A 256x64 + B 256x64) bf16
// stored as 16x32 swizzled subtiles (1024B each = one wave gload_lds).
// ksplit=2: low bit of swizzled wg id selects K-segment; EPI=3 stores fp32
// partial at outf + kseg*M*N (reduced by addred_k).
#define DS_A(BUF, SM, KK) (*(const bf16x8*)(ldsb + (BUF)*32768 + \
        ((((SM)*2) + (KK)) << 10) + rin64 + cst2))
#define DS_B(BUF, SN, KK) (*(const bf16x8*)(ldsb + 65536 + (BUF)*32768 + \
        ((((SN)*2) + (KK)) << 10) + rin64 + cst2))
#define STAGE_A(BUF, SK, KT) do { \
    gload_lds16(sA0 + ((long)(KT)*64 + (SK)*32), ldsb + (BUF)*32768 + (w4 + (SK))*1024); \
    gload_lds16(sA1 + ((long)(KT)*64 + (SK)*32), ldsb + (BUF)*32768 + (w4 + 2 + (SK))*1024); \
} while (0)
#define STAGE_B(BUF, SK, KT) do { \
    gload_lds16(sB0 + ((long)(KT)*64 + (SK)*32), ldsb + 65536 + (BUF)*32768 + (w4 + (SK))*1024); \
    gload_lds16(sB1 + ((long)(KT)*64 + (SK)*32), ldsb + 65536 + (BUF)*32768 + (w4 + 2 + (SK))*1024); \
} while (0)
#define PHASE(BUF, MH, KK, RDB, STAGE_STMT, VM) do { \
    bf16x8 af[4]; \
    _Pragma("unroll") \
    for (int m = 0; m < 4; ++m) af[m] = DS_A(BUF, wr8 + (MH)*4 + m, KK); \
    if (RDB) { \
        bfr[0] = DS_B(BUF, wc4 + 0, KK); bfr[1] = DS_B(BUF, wc4 + 1, KK); \
        bfr[2] = DS_B(BUF, wc4 + 2, KK); bfr[3] = DS_B(BUF, wc4 + 3, KK); \
    } \
    STAGE_STMT; \
    if (VM) { asm volatile("s_waitcnt vmcnt(6)" ::: "memory"); } \
    __builtin_amdgcn_sched_barrier(0); \
    __builtin_amdgcn_s_barrier(); \
    __builtin_amdgcn_sched_barrier(0); \
    __builtin_amdgcn_s_setprio(1); \
    _Pragma("unroll") \
    for (int m = 0; m < 4; ++m) \
        _Pragma("unroll") \
        for (int n = 0; n < 4; ++n) \
            acc[(MH)*4 + m][n] = MFMA16(af[m], bfr[n], acc[(MH)*4 + m][n], 0, 0, 0); \
    __builtin_amdgcn_s_setprio(0); \
    __builtin_amdgcn_sched_barrier(0); \
    __builtin_amdgcn_s_barrier(); \
    __builtin_amdgcn_sched_barrier(0); \
} while (0)

template <int EPI>
__global__ __launch_bounds__(512, 2) void gemm256(const u16* __restrict__ A,
                                                  const u16* __restrict__ W,
                                                  int M, int N, int K,
                                                  u16* outb, float* outf,
                                                  const float* res, int ksplit) {
    __shared__ u16 lds_[65536];
    char* ldsb = (char*)lds_;
    const int tid = threadIdx.x;
    const int w = tid >> 6, l = tid & 63;
    const int w4 = w * 4;
    const int wr8 = (w >> 2) * 8;      // A subtile base (wave M-half)
    const int wc4 = (w & 3) * 4;       // B subtile base (wave N-quarter)
    const int rin64 = (l & 15) * 64;
    const int cst2 = ((((l >> 4) * 8) ^ (((l >> 3) & 1) << 4)) << 1);

    // XCD-aware bijective swizzle (nwg % 8 == 0 for all our shapes)
    const int nbn = N >> 8;
    const int nwg = gridDim.x;
    const int cpx = nwg >> 3;
    const int bid = blockIdx.x;
    int wg = (bid & 7) * cpx + (bid >> 3);
    int kseg = 0;
    int Keff = K;
    if (ksplit == 2) {
        kseg = wg & 1;
        wg >>= 1;
        Keff = K >> 1;
    }
    const int bm = wg / nbn, bn = wg % nbn;
    const u16* Ab = A + (long)kseg * Keff;
    const u16* Wb = W + (long)kseg * Keff;

    // staging source pointers: lane l covers subtile row r4=l>>2, chunk (l&3)*8
    const int r4 = l >> 2;
    const int clog = ((l & 3) * 8) ^ (((r4 >> 3) & 1) << 4);
    const u16* sA0 = Ab + ((long)bm * 256 + (w * 2 + 0) * 16 + r4) * K + clog;
    const u16* sA1 = Ab + ((long)bm * 256 + (w * 2 + 1) * 16 + r4) * K + clog;
    const u16* sB0 = Wb + ((long)bn * 256 + (w * 2 + 0) * 16 + r4) * K + clog;
    const u16* sB1 = Wb + ((long)bn * 256 + (w * 2 + 1) * 16 + r4) * K + clog;

    f32x4 acc[8][4];
    #pragma unroll
    for (int m = 0; m < 8; ++m)
        #pragma unroll
        for (int n = 0; n < 4; ++n) acc[m][n] = (f32x4){0.f, 0.f, 0.f, 0.f};
    bf16x8 bfr[4];

    const int nkt = Keff >> 6;
    const int niter = nkt >> 1;

    // prologue: tile0 full into buf0; tile1 {B0,A0,B1} into buf1
    STAGE_B(0, 0, 0); STAGE_A(0, 0, 0); STAGE_B(0, 1, 0); STAGE_A(0, 1, 0);
    STAGE_B(1, 0, 1); STAGE_A(1, 0, 1); STAGE_B(1, 1, 1);
    asm volatile("s_waitcnt vmcnt(6)" ::: "memory");
    __builtin_amdgcn_sched_barrier(0);
    __builtin_amdgcn_s_barrier();
    __builtin_amdgcn_sched_barrier(0);

    for (int it = 0; it < niter; ++it) {
        const int t = it * 2;
        const int t1 = t + 1;
        const int t2 = (t + 2 < nkt) ? t + 2 : nkt - 1;
        const int t3 = (t + 3 < nkt) ? t + 3 : nkt - 1;
        PHASE(0, 0, 0, 1, STAGE_A(1, 1, t1), 0);
        PHASE(0, 1, 0, 0, STAGE_B(0, 0, t2), 0);
        PHASE(0, 0, 1, 1, STAGE_A(0, 0, t2), 0);
        PHASE(0, 1, 1, 0, STAGE_B(0, 1, t2), 1);
        PHASE(1, 0, 0, 1, STAGE_A(0, 1, t2), 0);
        PHASE(1, 1, 0, 0, STAGE_B(1, 0, t3), 0);
        PHASE(1, 0, 1, 1, STAGE_A(1, 0, t3), 0);
        PHASE(1, 1, 1, 0, STAGE_B(1, 1, t3), 1);
    }
    asm volatile("s_waitcnt vmcnt(0)" ::: "memory");

    // epilogue
    const int rb = bm * 256 + (wr8 >> 3) * 128 + ((l >> 4) << 2);
    const int cb = bn * 256 + (w & 3) * 64 + (l & 15);
    float* pf = (EPI == 3) ? (outf + (long)kseg * M * N) : outf;
    #pragma unroll
    for (int m = 0; m < 8; ++m) {
        #pragma unroll
        for (int r = 0; r < 4; ++r) {
            long row = rb + m * 16 + r;
            #pragma unroll
            for (int n = 0; n < 4; ++n) {
                long col = cb + n * 16;
                float v = acc[m][n][r];
                if (EPI == 1) {
                    pf[row * N + col] = res[row * N + col] + v;
                } else if (EPI == 2) {
                    float u = 0.7978845608028654f * v * (1.0f + 0.044715f * v * v);
                    float e = __expf(2.0f * u);
                    float tgl = 1.0f - 2.0f / (e + 1.0f);
                    outb[row * N + col] = f2b(0.5f * v * (1.0f + tgl));
                } else if (EPI == 3) {
                    pf[row * N + col] = v;
                } else {
                    outb[row * N + col] = f2b(v);
                }
            }
        }
    }
}

// ---------------- causal flash attention v2 ----------------------------------
struct AttnState {
    f32x16 acc[4];
    float m_i, l_i;
};

template <bool DIAG>
static __device__ __forceinline__ void attn_tile(
    int kv0, int qg, int wave, int l31, int hi,
    const u16* __restrict__ Ks, const u16* __restrict__ Vt,
    const bf16x8 (&qf)[8], AttnState& st)
{
    const bool do_g1 = !(DIAG && wave == 0);
    f32x16 sacc0, sacc1;
    #pragma unroll
    for (int r = 0; r < 16; ++r) { sacc0[r] = 0.f; sacc1[r] = 0.f; }

    #pragma unroll
    for (int dsl = 0; dsl < 8; ++dsl) {
        int slot = dsl * 2 + hi;
        int kv = l31;
        int sw = (slot & 8) | ((slot & 7) ^ (kv & 7));
        bf16x8 kf = *(const bf16x8*)(Ks + kv * 128 + sw * 8);
        sacc0 = MFMA32(kf, qf[dsl], sacc0, 0, 0, 0);
    }
    if (do_g1) {
        #pragma unroll
        for (int dsl = 0; dsl < 8; ++dsl) {
            int slot = dsl * 2 + hi;
            int kv = 32 + l31;
            int sw = (slot & 8) | ((slot & 7) ^ (kv & 7));
            bf16x8 kf = *(const bf16x8*)(Ks + kv * 128 + sw * 8);
            sacc1 = MFMA32(kf, qf[dsl], sacc1, 0, 0, 0);
        }
    }

    float sv[2][16];
    #pragma unroll
    for (int r = 0; r < 16; ++r) {
        sv[0][r] = sacc0[r];
        sv[1][r] = do_g1 ? sacc1[r] : -INFINITY;
    }
    if (DIAG) {
        #pragma unroll
        for (int g = 0; g < 2; ++g)
            #pragma unroll
            for (int r = 0; r < 16; ++r) {
                int kvg = kv0 + g * 32 + ((r & 3) + 8 * (r >> 2) + 4 * hi);
                if (kvg > qg) sv[g][r] = -INFINITY;
            }
    }

    float mx = sv[0][0];
    #pragma unroll
    for (int r = 1; r < 16; ++r) mx = fmaxf(mx, sv[0][r]);
    #pragma unroll
    for (int r = 0; r < 16; ++r) mx = fmaxf(mx, sv[1][r]);
    mx = fmaxf(mx, __shfl_xor(mx, 32));

    bool defer = __all(mx <= st.m_i + 8.0f);
    if (!defer) {
        float mnew = fmaxf(st.m_i, mx);
        float f = __expf(st.m_i - mnew);
        st.l_i *= f;
        #pragma unroll
        for (int dblk = 0; dblk < 4; ++dblk)
            #pragma unroll
            for (int r = 0; r < 16; ++r) st.acc[dblk][r] *= f;
        st.m_i = mnew;
    }

    float ssum = 0.f;
    #pragma unroll
    for (int g = 0; g < 2; ++g)
        #pragma unroll
        for (int r = 0; r < 16; ++r) {
            float e = __expf(sv[g][r] - st.m_i);
            sv[g][r] = e;
            ssum += e;
        }
    ssum += __shfl_xor(ssum, 32);
    st.l_i += ssum;

    unsigned w[2][4][2];
    #pragma unroll
    for (int g = 0; g < 2; ++g)
        #pragma unroll
        for (int q4 = 0; q4 < 4; ++q4) {
            w[g][q4][0] = pk2(sv[g][4 * q4 + 0], sv[g][4 * q4 + 1]);
            w[g][q4][1] = pk2(sv[g][4 * q4 + 2], sv[g][4 * q4 + 3]);
        }
    bf16x8 pfrag[4];
    #pragma unroll
    for (int ks = 0; ks < 4; ++ks) {
        int g = ks >> 1, h2 = ks & 1;
        unsigned o0 = hi ? w[g][2 * h2 + 1][0] : w[g][2 * h2][0];
        unsigned o1 = hi ? w[g][2 * h2 + 1][1] : w[g][2 * h2][1];
        unsigned t0 = hi ? w[g][2 * h2][0] : w[g][2 * h2 + 1][0];
        unsigned t1 = hi ? w[g][2 * h2][1] : w[g][2 * h2 + 1][1];
        unsigned s0v = __shfl_xor(t0, 32);
        unsigned s1v = __shfl_xor(t1, 32);
        union { unsigned u[4]; bf16x8 v; } cv;
        cv.u[0] = hi ? s0v : o0;
        cv.u[1] = hi ? s1v : o1;
        cv.u[2] = hi ? o0 : s0v;
        cv.u[3] = hi ? o1 : s1v;
        pfrag[ks] = cv.v;
    }

    #pragma unroll
    for (int dblk = 0; dblk < 4; ++dblk) {
        int d = dblk * 32 + l31;
        #pragma unroll
        for (int ks = 0; ks < 4; ++ks) {
            if (ks >= 2 && !do_g1) continue;
            int slot = ks * 2 + hi;
            bf16x8 vf = *(const bf16x8*)(Vt + d * 64 + (slot ^ (d & 7)) * 8);
            st.acc[dblk] = MFMA32(vf, pfrag[ks], st.acc[dblk], 0, 0, 0);
        }
    }
}

__global__ __launch_bounds__(128) void attn2_k(const u16* __restrict__ qkv,
                                               const u16* __restrict__ vt,
                                               u16* __restrict__ out) {
    const int bh = blockIdx.y;
    const int b = bh >> 4, h = bh & 15;
    const int qb = blockIdx.x;
    const int q0 = qb * 64;
    const int tid = threadIdx.x, wave = tid >> 6, lane = tid & 63;
    const int l31 = lane & 31, hi = lane >> 5;
    const int brow = b * 2048;
    __shared__ u16 Ks_lds[64 * 128];
    __shared__ u16 Vt_lds[128 * 64];

    bf16x8 qf[8];
    {
        const u16* qp = qkv + (long)(brow + q0 + wave * 32 + l31) * 6144 +
                        h * 128 + hi * 8;
        #pragma unroll
        for (int dsl = 0; dsl < 8; ++dsl) qf[dsl] = *(const bf16x8*)(qp + dsl * 16);
    }

    AttnState st;
    st.m_i = -INFINITY; st.l_i = 0.f;
    #pragma unroll
    for (int dblk = 0; dblk < 4; ++dblk)
        #pragma unroll
        for (int r = 0; r < 16; ++r) st.acc[dblk][r] = 0.f;

    const int qg = q0 + wave * 32 + l31;

    for (int t = 0; t <= qb; ++t) {
        const int kv0 = t * 64;
        __syncthreads();
        #pragma unroll
        for (int i = 0; i < 8; ++i) {
            int kv = wave * 32 + i * 4 + (lane >> 4);
            int slot = lane & 15;
            int sw = (slot & 8) | ((slot & 7) ^ (kv & 7));
            const u16* src = qkv + (long)(brow + kv0 + kv) * 6144 + 2048 +
                             h * 128 + sw * 8;
            gload_lds16(src, (char*)Ks_lds + (wave * 32 + i * 4) * 256);
        }
        #pragma unroll
        for (int i = 0; i < 8; ++i) {
            int d = wave * 64 + i * 8 + (lane >> 3);
            int slot = lane & 7;
            int sw = slot ^ (d & 7);
            const u16* src = vt + ((long)bh * 128 + d) * 2048 + kv0 + sw * 8;
            gload_lds16(src, (char*)Vt_lds + (wave * 64 + i * 8) * 128);
        }
        __syncthreads();
        if (t < qb)
            attn_tile<false>(kv0, qg, wave, l31, hi, Ks_lds, Vt_lds, qf, st);
        else
            attn_tile<true>(kv0, qg, wave, l31, hi, Ks_lds, Vt_lds, qf, st);
    }

    float inv = 1.0f / st.l_i;
    long orow = (long)(brow + q0 + wave * 32 + l31);
    #pragma unroll
    for (int dblk = 0; dblk < 4; ++dblk)
        #pragma unroll
        for (int rq = 0; rq < 4; ++rq) {
            u16x4 o4;
            #pragma unroll
            for (int m = 0; m < 4; ++m) o4[m] = f2b(st.acc[dblk][rq * 4 + m] * inv);
            int d = dblk * 32 + 8 * rq + 4 * hi;
            *(u16x4*)(out + orow * 2048 + h * 128 + d) = o4;
        }
}

// ---------------- launch --------------------------------------------------
extern "C" void kernel_launch(void* const* d_in, const int* in_sizes, int n_in,
                              void* d_out, int out_size, void* d_ws, size_t ws_size,
                              hipStream_t stream) {
    const float* x     = (const float*)d_in[0];
    const float* cosb  = (const float*)d_in[1];
    const float* sinb  = (const float*)d_in[2];
    const float* g1    = (const float*)d_in[3];
    const float* g2    = (const float*)d_in[4];
    const float* w_qkv = (const float*)d_in[5];
    const float* w_out = (const float*)d_in[6];
    const float* w_fc1 = (const float*)d_in[7];
    const float* w_fc2 = (const float*)d_in[8];

    char* ws = (char*)d_ws;
    u16* wqkv_b = (u16*)(ws);                    // 6144x2048 bf16
    u16* wout_b = (u16*)(ws + 25165824);         // 2048x2048
    u16* wfc1_b = (u16*)(ws + 33554432);         // 8192x2048
    u16* wfc2_b = (u16*)(ws + 67108864);         // 2048x8192
    u16* h_b    = (u16*)(ws + 100663296);        // 4096x2048 (h1 / vt / h2)
    u16* qkv_b  = (u16*)(ws + 117440512);        // 4096x6144
    u16* attn_b = (u16*)(ws + 167772160);        // 4096x2048
    u16* vt_b   = h_b;                           // 32x128x2048 (after qkv GEMM)
    u16* hg_b   = qkv_b;                         // 4096x8192, reuses qkv+attn
    float* part = (float*)ws;                    // fc2 split-K partials, 2x33.5MB
                                                 // (reuses dead wqkv/wout/wfc1
                                                 //  regions; rewritten by cvt
                                                 //  at the start of every call)
    float* xout = (float*)d_out;

    cvt_k<<<12288, 256, 0, stream>>>(w_qkv, wqkv_b, 12582912L);
    cvt_k<<<4096, 256, 0, stream>>>(w_out, wout_b, 4194304L);
    cvt_k<<<16384, 256, 0, stream>>>(w_fc1, wfc1_b, 16777216L);
    cvt_k<<<16384, 256, 0, stream>>>(w_fc2, wfc2_b, 16777216L);

    rmsnorm_k<<<4096, 256, 0, stream>>>(x, g1, h_b);
    gemm256<0><<<384, 512, 0, stream>>>(h_b, wqkv_b, 4096, 6144, 2048,
                                        qkv_b, nullptr, nullptr, 1);
    rope_k<<<8192, 256, 0, stream>>>(qkv_b, cosb, sinb);
    vtrans_k<<<dim3(32, 32), 256, 0, stream>>>(qkv_b, vt_b);
    attn2_k<<<dim3(32, 32), 128, 0, stream>>>(qkv_b, vt_b, attn_b);
    gemm_bt<1><<<dim3(16, 32), 256, 0, stream>>>(attn_b, wout_b, 4096, 2048, 2048,
                                                 nullptr, xout, x);
    rmsnorm_k<<<4096, 256, 0, stream>>>(xout, g2, h_b);
    gemm256<2><<<512, 512, 0, stream>>>(h_b, wfc1_b, 4096, 8192, 2048,
                                        hg_b, nullptr, nullptr, 1);
    gemm256<3><<<256, 512, 0, stream>>>(hg_b, wfc2_b, 4096, 2048, 8192,
                                        nullptr, part, nullptr, 2);
    addred_k<<<8192, 256, 0, stream>>>(xout, part, part + 8388608);
}

// Round 5
// 677.044 us; speedup vs baseline: 1.6348x; 1.0142x over previous
//
#include <hip/hip_runtime.h>
#include <stdint.h>

typedef unsigned short u16;
typedef u16 u16x4 __attribute__((ext_vector_type(4)));
typedef u16 u16x8 __attribute__((ext_vector_type(8)));
typedef __bf16 bf16x8 __attribute__((ext_vector_type(8)));
typedef float f32x4 __attribute__((ext_vector_type(4)));
typedef float f32x16 __attribute__((ext_vector_type(16)));

#define MFMA16 __builtin_amdgcn_mfma_f32_16x16x32_bf16
#define MFMA32 __builtin_amdgcn_mfma_f32_32x32x16_bf16

static __device__ __forceinline__ float b2f(u16 u) {
    union { unsigned int i; float f; } v; v.i = ((unsigned int)u) << 16; return v.f;
}
static __device__ __forceinline__ u16 f2b(float f) {
    union { float f; unsigned int i; } v; v.f = f;
    unsigned int r = (v.i + 0x7fffu + ((v.i >> 16) & 1u)) >> 16;
    return (u16)r;
}
static __device__ __forceinline__ unsigned pk2(float lo, float hi) {
    union { __bf16 b[2]; unsigned u; } t;
    t.b[0] = (__bf16)lo; t.b[1] = (__bf16)hi; return t.u;
}
static __device__ __forceinline__ void gload_lds16(const void* g, void* l) {
    __builtin_amdgcn_global_load_lds((__attribute__((address_space(1))) void*)g,
                                     (__attribute__((address_space(3))) void*)l,
                                     16, 0, 0);
}

// ---------------- fp32 -> bf16 weight conversion ----------------
__global__ __launch_bounds__(256) void cvt_k(const float* __restrict__ in,
                                             u16* __restrict__ out, long n) {
    long i = ((long)blockIdx.x * 256 + threadIdx.x) * 4;
    if (i >= n) return;
    float4 v = *(const float4*)(in + i);
    u16x4 o; o[0] = f2b(v.x); o[1] = f2b(v.y); o[2] = f2b(v.z); o[3] = f2b(v.w);
    *(u16x4*)(out + i) = o;
}

// ---------------- split-K reduce: xout += p0 + p1 ----------------------------
__global__ __launch_bounds__(256) void addred_k(float* __restrict__ xout,
                                                const float* __restrict__ p0,
                                                const float* __restrict__ p1) {
    long i = ((long)blockIdx.x * 256 + threadIdx.x) * 4;
    float4 a = *(const float4*)(xout + i);
    float4 b = *(const float4*)(p0 + i);
    float4 c = *(const float4*)(p1 + i);
    a.x += b.x + c.x; a.y += b.y + c.y; a.z += b.z + c.z; a.w += b.w + c.w;
    *(float4*)(xout + i) = a;
}

// ---------------- split-K reduce with residual: xout = x + p0 + p1 -----------
__global__ __launch_bounds__(256) void addred2_k(float* __restrict__ xout,
                                                 const float* __restrict__ x,
                                                 const float* __restrict__ p0,
                                                 const float* __restrict__ p1) {
    long i = ((long)blockIdx.x * 256 + threadIdx.x) * 4;
    float4 r = *(const float4*)(x + i);
    float4 b = *(const float4*)(p0 + i);
    float4 c = *(const float4*)(p1 + i);
    r.x += b.x + c.x; r.y += b.y + c.y; r.z += b.z + c.z; r.w += b.w + c.w;
    *(float4*)(xout + i) = r;
}

// ---------------- RMSNorm: fp32 in -> bf16 out (D=2048) ----------------------
__global__ __launch_bounds__(256) void rmsnorm_k(const float* __restrict__ x,
                                                 const float* __restrict__ g,
                                                 u16* __restrict__ out) {
    const long row = blockIdx.x;
    const int tid = threadIdx.x;
    const float* xr = x + row * 2048;
    float4 a = *(const float4*)(xr + tid * 4);
    float4 b = *(const float4*)(xr + 1024 + tid * 4);
    float ss = a.x*a.x + a.y*a.y + a.z*a.z + a.w*a.w
             + b.x*b.x + b.y*b.y + b.z*b.z + b.w*b.w;
    #pragma unroll
    for (int d = 1; d < 64; d <<= 1) ss += __shfl_xor(ss, d);
    __shared__ float red[4];
    if ((tid & 63) == 0) red[tid >> 6] = ss;
    __syncthreads();
    float tot = red[0] + red[1] + red[2] + red[3];
    float rinv = rsqrtf(tot * (1.0f / 2048.0f) + 1e-6f);
    float4 g0 = *(const float4*)(g + tid * 4);
    float4 g1 = *(const float4*)(g + 1024 + tid * 4);
    u16x4 o0, o1;
    o0[0] = f2b(a.x * g0.x * rinv); o0[1] = f2b(a.y * g0.y * rinv);
    o0[2] = f2b(a.z * g0.z * rinv); o0[3] = f2b(a.w * g0.w * rinv);
    o1[0] = f2b(b.x * g1.x * rinv); o1[1] = f2b(b.y * g1.y * rinv);
    o1[2] = f2b(b.z * g1.z * rinv); o1[3] = f2b(b.w * g1.w * rinv);
    *(u16x4*)(out + row * 2048 + tid * 4) = o0;
    *(u16x4*)(out + row * 2048 + 1024 + tid * 4) = o1;
}

// ---------------- RoPE in-place on bf16 qkv; q additionally scaled ------------
__global__ __launch_bounds__(256) void rope_k(u16* __restrict__ qkv,
                                              const float* __restrict__ cosb,
                                              const float* __restrict__ sinb) {
    long idx = (long)blockIdx.x * 256 + threadIdx.x;
    int d = (int)(idx & 15) * 4;
    int h = (int)((idx >> 4) & 15);
    int which = (int)((idx >> 8) & 1);
    long row = idx >> 9;
    int s = (int)(row & 2047);
    u16* base = qkv + row * 6144 + which * 2048 + h * 128;
    u16x4 ua = *(u16x4*)(base + d);
    u16x4 ub = *(u16x4*)(base + d + 64);
    float4 c4 = *(const float4*)(cosb + (long)s * 128 + d);
    float4 s4 = *(const float4*)(sinb + (long)s * 128 + d);
    float cc[4] = {c4.x, c4.y, c4.z, c4.w};
    float sn[4] = {s4.x, s4.y, s4.z, s4.w};
    float scale = (which == 0) ? 0.08838834764831845f : 1.0f;
    u16x4 oa, ob;
    #pragma unroll
    for (int j = 0; j < 4; ++j) {
        float a = b2f(ua[j]), b = b2f(ub[j]);
        oa[j] = f2b((a * cc[j] - b * sn[j]) * scale);
        ob[j] = f2b((b * cc[j] + a * sn[j]) * scale);
    }
    *(u16x4*)(base + d) = oa;
    *(u16x4*)(base + d + 64) = ob;
}

// ---------------- V transpose: qkv V section -> vt[bh][d][s] -----------------
__global__ __launch_bounds__(256) void vtrans_k(const u16* __restrict__ qkv,
                                                u16* __restrict__ vt) {
    __shared__ u16 t[128 * 65];
    const int bh = blockIdx.y, b = bh >> 4, h = bh & 15;
    const int s0 = blockIdx.x * 64;
    const int tid = threadIdx.x;
    #pragma unroll
    for (int it = 0; it < 4; ++it) {
        int flat = it * 256 + tid;
        int sl = flat >> 4, slot = flat & 15;
        u16x8 v = *(const u16x8*)(qkv + (long)(b * 2048 + s0 + sl) * 6144 + 4096 +
                                  h * 128 + slot * 8);
        #pragma unroll
        for (int j = 0; j < 8; ++j) t[(slot * 8 + j) * 65 + sl] = v[j];
    }
    __syncthreads();
    #pragma unroll
    for (int it = 0; it < 4; ++it) {
        int flat = it * 256 + tid;
        int d = flat >> 3, sg = flat & 7;
        u16x8 v;
        #pragma unroll
        for (int j = 0; j < 8; ++j) v[j] = t[d * 65 + sg * 8 + j];
        *(u16x8*)(vt + ((long)bh * 128 + d) * 2048 + s0 + sg * 8) = v;
    }
}

// ---------------- GEMM 256x256, 8-phase counted-vmcnt pipeline ---------------
// 512 thr = 8 waves (2M x 4N), BK=64, LDS = 2 buf x (A 256x64 + B 256x64) bf16
// stored as 16x32 swizzled subtiles (1024B each = one wave gload_lds).
// ksplit=2: low bit of swizzled wg id selects K-segment; EPI=3 stores fp32
// partial at outf + kseg*M*N (reduced by addred*_k).
// GM=8 grouping: each XCD's contiguous wg chunk covers an 8-bm-row sub-block
// (bn-major within the group) so its private L2 sees ~8 A panels + few B
// panels instead of the whole weight matrix.
#define DS_A(BUF, SM, KK) (*(const bf16x8*)(ldsb + (BUF)*32768 + \
        ((((SM)*2) + (KK)) << 10) + rin64 + cst2))
#define DS_B(BUF, SN, KK) (*(const bf16x8*)(ldsb + 65536 + (BUF)*32768 + \
        ((((SN)*2) + (KK)) << 10) + rin64 + cst2))
#define STAGE_A(BUF, SK, KT) do { \
    gload_lds16(sA0 + ((long)(KT)*64 + (SK)*32), ldsb + (BUF)*32768 + (w4 + (SK))*1024); \
    gload_lds16(sA1 + ((long)(KT)*64 + (SK)*32), ldsb + (BUF)*32768 + (w4 + 2 + (SK))*1024); \
} while (0)
#define STAGE_B(BUF, SK, KT) do { \
    gload_lds16(sB0 + ((long)(KT)*64 + (SK)*32), ldsb + 65536 + (BUF)*32768 + (w4 + (SK))*1024); \
    gload_lds16(sB1 + ((long)(KT)*64 + (SK)*32), ldsb + 65536 + (BUF)*32768 + (w4 + 2 + (SK))*1024); \
} while (0)
#define PHASE(BUF, MH, KK, RDB, STAGE_STMT, VM) do { \
    bf16x8 af[4]; \
    _Pragma("unroll") \
    for (int m = 0; m < 4; ++m) af[m] = DS_A(BUF, wr8 + (MH)*4 + m, KK); \
    if (RDB) { \
        bfr[0] = DS_B(BUF, wc4 + 0, KK); bfr[1] = DS_B(BUF, wc4 + 1, KK); \
        bfr[2] = DS_B(BUF, wc4 + 2, KK); bfr[3] = DS_B(BUF, wc4 + 3, KK); \
    } \
    STAGE_STMT; \
    if (VM) { asm volatile("s_waitcnt vmcnt(6)" ::: "memory"); } \
    __builtin_amdgcn_sched_barrier(0); \
    __builtin_amdgcn_s_barrier(); \
    __builtin_amdgcn_sched_barrier(0); \
    __builtin_amdgcn_s_setprio(1); \
    _Pragma("unroll") \
    for (int m = 0; m < 4; ++m) \
        _Pragma("unroll") \
        for (int n = 0; n < 4; ++n) \
            acc[(MH)*4 + m][n] = MFMA16(af[m], bfr[n], acc[(MH)*4 + m][n], 0, 0, 0); \
    __builtin_amdgcn_s_setprio(0); \
    __builtin_amdgcn_sched_barrier(0); \
    __builtin_amdgcn_s_barrier(); \
    __builtin_amdgcn_sched_barrier(0); \
} while (0)

template <int EPI>
__global__ __launch_bounds__(512, 2) void gemm256(const u16* __restrict__ A,
                                                  const u16* __restrict__ W,
                                                  int M, int N, int K,
                                                  u16* outb, float* outf,
                                                  const float* res, int ksplit) {
    __shared__ u16 lds_[65536];
    char* ldsb = (char*)lds_;
    const int tid = threadIdx.x;
    const int w = tid >> 6, l = tid & 63;
    const int w4 = w * 4;
    const int wr8 = (w >> 2) * 8;      // A subtile base (wave M-half)
    const int wc4 = (w & 3) * 4;       // B subtile base (wave N-quarter)
    const int rin64 = (l & 15) * 64;
    const int cst2 = ((((l >> 4) * 8) ^ (((l >> 3) & 1) << 4)) << 1);

    // XCD-aware bijective swizzle (nwg % 8 == 0 for all our shapes)
    const int nbn = N >> 8;
    const int nbm = M >> 8;
    const int nwg = gridDim.x;
    const int cpx = nwg >> 3;
    const int bid = blockIdx.x;
    int wg = (bid & 7) * cpx + (bid >> 3);
    int kseg = 0;
    int Keff = K;
    if (ksplit == 2) {
        kseg = wg & 1;
        wg >>= 1;
        Keff = K >> 1;
    }
    // GM=8 grouping (bn-major within 8 bm-rows) for per-XCD L2 locality
    const int grp = 8 * nbn;
    const int g8 = wg / grp;
    const int rem = wg - g8 * grp;
    const int bm0 = g8 * 8;
    const int gmh = (nbm - bm0 < 8) ? (nbm - bm0) : 8;
    const int bn = rem / gmh;
    const int bm = bm0 + rem % gmh;
    const u16* Ab = A + (long)kseg * Keff;
    const u16* Wb = W + (long)kseg * Keff;

    // staging source pointers: lane l covers subtile row r4=l>>2, chunk (l&3)*8
    const int r4 = l >> 2;
    const int clog = ((l & 3) * 8) ^ (((r4 >> 3) & 1) << 4);
    const u16* sA0 = Ab + ((long)bm * 256 + (w * 2 + 0) * 16 + r4) * K + clog;
    const u16* sA1 = Ab + ((long)bm * 256 + (w * 2 + 1) * 16 + r4) * K + clog;
    const u16* sB0 = Wb + ((long)bn * 256 + (w * 2 + 0) * 16 + r4) * K + clog;
    const u16* sB1 = Wb + ((long)bn * 256 + (w * 2 + 1) * 16 + r4) * K + clog;

    f32x4 acc[8][4];
    #pragma unroll
    for (int m = 0; m < 8; ++m)
        #pragma unroll
        for (int n = 0; n < 4; ++n) acc[m][n] = (f32x4){0.f, 0.f, 0.f, 0.f};
    bf16x8 bfr[4];

    const int nkt = Keff >> 6;
    const int niter = nkt >> 1;

    // prologue: tile0 full into buf0; tile1 {B0,A0,B1} into buf1
    STAGE_B(0, 0, 0); STAGE_A(0, 0, 0); STAGE_B(0, 1, 0); STAGE_A(0, 1, 0);
    STAGE_B(1, 0, 1); STAGE_A(1, 0, 1); STAGE_B(1, 1, 1);
    asm volatile("s_waitcnt vmcnt(6)" ::: "memory");
    __builtin_amdgcn_sched_barrier(0);
    __builtin_amdgcn_s_barrier();
    __builtin_amdgcn_sched_barrier(0);

    for (int it = 0; it < niter; ++it) {
        const int t = it * 2;
        const int t1 = t + 1;
        const int t2 = (t + 2 < nkt) ? t + 2 : nkt - 1;
        const int t3 = (t + 3 < nkt) ? t + 3 : nkt - 1;
        PHASE(0, 0, 0, 1, STAGE_A(1, 1, t1), 0);
        PHASE(0, 1, 0, 0, STAGE_B(0, 0, t2), 0);
        PHASE(0, 0, 1, 1, STAGE_A(0, 0, t2), 0);
        PHASE(0, 1, 1, 0, STAGE_B(0, 1, t2), 1);
        PHASE(1, 0, 0, 1, STAGE_A(0, 1, t2), 0);
        PHASE(1, 1, 0, 0, STAGE_B(1, 0, t3), 0);
        PHASE(1, 0, 1, 1, STAGE_A(1, 0, t3), 0);
        PHASE(1, 1, 1, 0, STAGE_B(1, 1, t3), 1);
    }
    asm volatile("s_waitcnt vmcnt(0)" ::: "memory");

    // epilogue
    const int rb = bm * 256 + (wr8 >> 3) * 128 + ((l >> 4) << 2);
    const int cb = bn * 256 + (w & 3) * 64 + (l & 15);
    float* pf = (EPI == 3) ? (outf + (long)kseg * M * N) : outf;
    #pragma unroll
    for (int m = 0; m < 8; ++m) {
        #pragma unroll
        for (int r = 0; r < 4; ++r) {
            long row = rb + m * 16 + r;
            #pragma unroll
            for (int n = 0; n < 4; ++n) {
                long col = cb + n * 16;
                float v = acc[m][n][r];
                if (EPI == 1) {
                    pf[row * N + col] = res[row * N + col] + v;
                } else if (EPI == 2) {
                    float u = 0.7978845608028654f * v * (1.0f + 0.044715f * v * v);
                    float e = __expf(2.0f * u);
                    float tgl = 1.0f - 2.0f / (e + 1.0f);
                    outb[row * N + col] = f2b(0.5f * v * (1.0f + tgl));
                } else if (EPI == 3) {
                    pf[row * N + col] = v;
                } else {
                    outb[row * N + col] = f2b(v);
                }
            }
        }
    }
}

// ---------------- causal flash attention v2 ----------------------------------
struct AttnState {
    f32x16 acc[4];
    float m_i, l_i;
};

template <bool DIAG>
static __device__ __forceinline__ void attn_tile(
    int kv0, int qg, int wave, int l31, int hi,
    const u16* __restrict__ Ks, const u16* __restrict__ Vt,
    const bf16x8 (&qf)[8], AttnState& st)
{
    const bool do_g1 = !(DIAG && wave == 0);
    f32x16 sacc0, sacc1;
    #pragma unroll
    for (int r = 0; r < 16; ++r) { sacc0[r] = 0.f; sacc1[r] = 0.f; }

    #pragma unroll
    for (int dsl = 0; dsl < 8; ++dsl) {
        int slot = dsl * 2 + hi;
        int kv = l31;
        int sw = (slot & 8) | ((slot & 7) ^ (kv & 7));
        bf16x8 kf = *(const bf16x8*)(Ks + kv * 128 + sw * 8);
        sacc0 = MFMA32(kf, qf[dsl], sacc0, 0, 0, 0);
    }
    if (do_g1) {
        #pragma unroll
        for (int dsl = 0; dsl < 8; ++dsl) {
            int slot = dsl * 2 + hi;
            int kv = 32 + l31;
            int sw = (slot & 8) | ((slot & 7) ^ (kv & 7));
            bf16x8 kf = *(const bf16x8*)(Ks + kv * 128 + sw * 8);
            sacc1 = MFMA32(kf, qf[dsl], sacc1, 0, 0, 0);
        }
    }

    float sv[2][16];
    #pragma unroll
    for (int r = 0; r < 16; ++r) {
        sv[0][r] = sacc0[r];
        sv[1][r] = do_g1 ? sacc1[r] : -INFINITY;
    }
    if (DIAG) {
        #pragma unroll
        for (int g = 0; g < 2; ++g)
            #pragma unroll
            for (int r = 0; r < 16; ++r) {
                int kvg = kv0 + g * 32 + ((r & 3) + 8 * (r >> 2) + 4 * hi);
                if (kvg > qg) sv[g][r] = -INFINITY;
            }
    }

    float mx = sv[0][0];
    #pragma unroll
    for (int r = 1; r < 16; ++r) mx = fmaxf(mx, sv[0][r]);
    #pragma unroll
    for (int r = 0; r < 16; ++r) mx = fmaxf(mx, sv[1][r]);
    mx = fmaxf(mx, __shfl_xor(mx, 32));

    bool defer = __all(mx <= st.m_i + 8.0f);
    if (!defer) {
        float mnew = fmaxf(st.m_i, mx);
        float f = __expf(st.m_i - mnew);
        st.l_i *= f;
        #pragma unroll
        for (int dblk = 0; dblk < 4; ++dblk)
            #pragma unroll
            for (int r = 0; r < 16; ++r) st.acc[dblk][r] *= f;
        st.m_i = mnew;
    }

    float ssum = 0.f;
    #pragma unroll
    for (int g = 0; g < 2; ++g)
        #pragma unroll
        for (int r = 0; r < 16; ++r) {
            float e = __expf(sv[g][r] - st.m_i);
            sv[g][r] = e;
            ssum += e;
        }
    ssum += __shfl_xor(ssum, 32);
    st.l_i += ssum;

    unsigned w[2][4][2];
    #pragma unroll
    for (int g = 0; g < 2; ++g)
        #pragma unroll
        for (int q4 = 0; q4 < 4; ++q4) {
            w[g][q4][0] = pk2(sv[g][4 * q4 + 0], sv[g][4 * q4 + 1]);
            w[g][q4][1] = pk2(sv[g][4 * q4 + 2], sv[g][4 * q4 + 3]);
        }
    bf16x8 pfrag[4];
    #pragma unroll
    for (int ks = 0; ks < 4; ++ks) {
        int g = ks >> 1, h2 = ks & 1;
        unsigned o0 = hi ? w[g][2 * h2 + 1][0] : w[g][2 * h2][0];
        unsigned o1 = hi ? w[g][2 * h2 + 1][1] : w[g][2 * h2][1];
        unsigned t0 = hi ? w[g][2 * h2][0] : w[g][2 * h2 + 1][0];
        unsigned t1 = hi ? w[g][2 * h2][1] : w[g][2 * h2 + 1][1];
        unsigned s0v = __shfl_xor(t0, 32);
        unsigned s1v = __shfl_xor(t1, 32);
        union { unsigned u[4]; bf16x8 v; } cv;
        cv.u[0] = hi ? s0v : o0;
        cv.u[1] = hi ? s1v : o1;
        cv.u[2] = hi ? o0 : s0v;
        cv.u[3] = hi ? o1 : s1v;
        pfrag[ks] = cv.v;
    }

    #pragma unroll
    for (int dblk = 0; dblk < 4; ++dblk) {
        int d = dblk * 32 + l31;
        #pragma unroll
        for (int ks = 0; ks < 4; ++ks) {
            if (ks >= 2 && !do_g1) continue;
            int slot = ks * 2 + hi;
            bf16x8 vf = *(const bf16x8*)(Vt + d * 64 + (slot ^ (d & 7)) * 8);
            st.acc[dblk] = MFMA32(vf, pfrag[ks], st.acc[dblk], 0, 0, 0);
        }
    }
}

__global__ __launch_bounds__(128) void attn2_k(const u16* __restrict__ qkv,
                                               const u16* __restrict__ vt,
                                               u16* __restrict__ out) {
    const int bh = blockIdx.y;
    const int b = bh >> 4, h = bh & 15;
    const int qb = blockIdx.x;
    const int q0 = qb * 64;
    const int tid = threadIdx.x, wave = tid >> 6, lane = tid & 63;
    const int l31 = lane & 31, hi = lane >> 5;
    const int brow = b * 2048;
    __shared__ u16 Ks_lds[64 * 128];
    __shared__ u16 Vt_lds[128 * 64];

    bf16x8 qf[8];
    {
        const u16* qp = qkv + (long)(brow + q0 + wave * 32 + l31) * 6144 +
                        h * 128 + hi * 8;
        #pragma unroll
        for (int dsl = 0; dsl < 8; ++dsl) qf[dsl] = *(const bf16x8*)(qp + dsl * 16);
    }

    AttnState st;
    st.m_i = -INFINITY; st.l_i = 0.f;
    #pragma unroll
    for (int dblk = 0; dblk < 4; ++dblk)
        #pragma unroll
        for (int r = 0; r < 16; ++r) st.acc[dblk][r] = 0.f;

    const int qg = q0 + wave * 32 + l31;

    for (int t = 0; t <= qb; ++t) {
        const int kv0 = t * 64;
        __syncthreads();
        #pragma unroll
        for (int i = 0; i < 8; ++i) {
            int kv = wave * 32 + i * 4 + (lane >> 4);
            int slot = lane & 15;
            int sw = (slot & 8) | ((slot & 7) ^ (kv & 7));
            const u16* src = qkv + (long)(brow + kv0 + kv) * 6144 + 2048 +
                             h * 128 + sw * 8;
            gload_lds16(src, (char*)Ks_lds + (wave * 32 + i * 4) * 256);
        }
        #pragma unroll
        for (int i = 0; i < 8; ++i) {
            int d = wave * 64 + i * 8 + (lane >> 3);
            int slot = lane & 7;
            int sw = slot ^ (d & 7);
            const u16* src = vt + ((long)bh * 128 + d) * 2048 + kv0 + sw * 8;
            gload_lds16(src, (char*)Vt_lds + (wave * 64 + i * 8) * 128);
        }
        __syncthreads();
        if (t < qb)
            attn_tile<false>(kv0, qg, wave, l31, hi, Ks_lds, Vt_lds, qf, st);
        else
            attn_tile<true>(kv0, qg, wave, l31, hi, Ks_lds, Vt_lds, qf, st);
    }

    float inv = 1.0f / st.l_i;
    long orow = (long)(brow + q0 + wave * 32 + l31);
    #pragma unroll
    for (int dblk = 0; dblk < 4; ++dblk)
        #pragma unroll
        for (int rq = 0; rq < 4; ++rq) {
            u16x4 o4;
            #pragma unroll
            for (int m = 0; m < 4; ++m) o4[m] = f2b(st.acc[dblk][rq * 4 + m] * inv);
            int d = dblk * 32 + 8 * rq + 4 * hi;
            *(u16x4*)(out + orow * 2048 + h * 128 + d) = o4;
        }
}

// ---------------- launch --------------------------------------------------
extern "C" void kernel_launch(void* const* d_in, const int* in_sizes, int n_in,
                              void* d_out, int out_size, void* d_ws, size_t ws_size,
                              hipStream_t stream) {
    const float* x     = (const float*)d_in[0];
    const float* cosb  = (const float*)d_in[1];
    const float* sinb  = (const float*)d_in[2];
    const float* g1    = (const float*)d_in[3];
    const float* g2    = (const float*)d_in[4];
    const float* w_qkv = (const float*)d_in[5];
    const float* w_out = (const float*)d_in[6];
    const float* w_fc1 = (const float*)d_in[7];
    const float* w_fc2 = (const float*)d_in[8];

    char* ws = (char*)d_ws;
    u16* wqkv_b = (u16*)(ws);                    // 6144x2048 bf16
    u16* wout_b = (u16*)(ws + 25165824);         // 2048x2048
    u16* wfc1_b = (u16*)(ws + 33554432);         // 8192x2048
    u16* wfc2_b = (u16*)(ws + 67108864);         // 2048x8192
    u16* h_b    = (u16*)(ws + 100663296);        // 4096x2048 (h1 / vt / h2)
    u16* qkv_b  = (u16*)(ws + 117440512);        // 4096x6144
    u16* attn_b = (u16*)(ws + 167772160);        // 4096x2048
    u16* vt_b   = h_b;                           // 32x128x2048 (after qkv GEMM)
    u16* hg_b   = qkv_b;                         // 4096x8192, reuses qkv+attn
    float* part = (float*)ws;                    // fc2 split-K partials, 2x33.5MB
                                                 // (dead wqkv/wout/wfc1 regions)
    float* pop  = (float*)(ws + 100663296);      // out-proj partials, 2x33.5MB
                                                 // (dead h_b+qkv regions, exact)
    float* xout = (float*)d_out;

    cvt_k<<<12288, 256, 0, stream>>>(w_qkv, wqkv_b, 12582912L);
    cvt_k<<<4096, 256, 0, stream>>>(w_out, wout_b, 4194304L);
    cvt_k<<<16384, 256, 0, stream>>>(w_fc1, wfc1_b, 16777216L);
    cvt_k<<<16384, 256, 0, stream>>>(w_fc2, wfc2_b, 16777216L);

    rmsnorm_k<<<4096, 256, 0, stream>>>(x, g1, h_b);
    gemm256<0><<<384, 512, 0, stream>>>(h_b, wqkv_b, 4096, 6144, 2048,
                                        qkv_b, nullptr, nullptr, 1);
    rope_k<<<8192, 256, 0, stream>>>(qkv_b, cosb, sinb);
    vtrans_k<<<dim3(32, 32), 256, 0, stream>>>(qkv_b, vt_b);
    attn2_k<<<dim3(32, 32), 128, 0, stream>>>(qkv_b, vt_b, attn_b);
    gemm256<3><<<256, 512, 0, stream>>>(attn_b, wout_b, 4096, 2048, 2048,
                                        nullptr, pop, nullptr, 2);
    addred2_k<<<8192, 256, 0, stream>>>(xout, x, pop, pop + 8388608);
    rmsnorm_k<<<4096, 256, 0, stream>>>(xout, g2, h_b);
    gemm256<2><<<512, 512, 0, stream>>>(h_b, wfc1_b, 4096, 8192, 2048,
                                        hg_b, nullptr, nullptr, 1);
    gemm256<3><<<256, 512, 0, stream>>>(hg_b, wfc2_b, 4096, 2048, 8192,
                                        nullptr, part, nullptr, 2);
    addred_k<<<8192, 256, 0, stream>>>(xout, part, part + 8388608);
}

// Round 6
// 604.729 us; speedup vs baseline: 1.8303x; 1.1196x over previous
//
#include <hip/hip_runtime.h>
#include <stdint.h>

typedef unsigned short u16;
typedef u16 u16x4 __attribute__((ext_vector_type(4)));
typedef u16 u16x8 __attribute__((ext_vector_type(8)));
typedef __bf16 bf16x8 __attribute__((ext_vector_type(8)));
typedef float f32x4 __attribute__((ext_vector_type(4)));
typedef float f32x16 __attribute__((ext_vector_type(16)));

#define MFMA16 __builtin_amdgcn_mfma_f32_16x16x32_bf16
#define MFMA32 __builtin_amdgcn_mfma_f32_32x32x16_bf16

static __device__ __forceinline__ float b2f(u16 u) {
    union { unsigned int i; float f; } v; v.i = ((unsigned int)u) << 16; return v.f;
}
static __device__ __forceinline__ u16 f2b(float f) {
    union { float f; unsigned int i; } v; v.f = f;
    unsigned int r = (v.i + 0x7fffu + ((v.i >> 16) & 1u)) >> 16;
    return (u16)r;
}
static __device__ __forceinline__ unsigned pk2(float lo, float hi) {
    union { __bf16 b[2]; unsigned u; } t;
    t.b[0] = (__bf16)lo; t.b[1] = (__bf16)hi; return t.u;
}
static __device__ __forceinline__ void gload_lds16(const void* g, void* l) {
    __builtin_amdgcn_global_load_lds((__attribute__((address_space(1))) void*)g,
                                     (__attribute__((address_space(3))) void*)l,
                                     16, 0, 0);
}

// ---------------- fp32 -> bf16 weight conversion ----------------
__global__ __launch_bounds__(256) void cvt_k(const float* __restrict__ in,
                                             u16* __restrict__ out, long n) {
    long i = ((long)blockIdx.x * 256 + threadIdx.x) * 4;
    if (i >= n) return;
    float4 v = *(const float4*)(in + i);
    u16x4 o; o[0] = f2b(v.x); o[1] = f2b(v.y); o[2] = f2b(v.z); o[3] = f2b(v.w);
    *(u16x4*)(out + i) = o;
}

// ---------------- split-K reduce: xout += p0 + p1 ----------------------------
__global__ __launch_bounds__(256) void addred_k(float* __restrict__ xout,
                                                const float* __restrict__ p0,
                                                const float* __restrict__ p1) {
    long i = ((long)blockIdx.x * 256 + threadIdx.x) * 4;
    float4 a = *(const float4*)(xout + i);
    float4 b = *(const float4*)(p0 + i);
    float4 c = *(const float4*)(p1 + i);
    a.x += b.x + c.x; a.y += b.y + c.y; a.z += b.z + c.z; a.w += b.w + c.w;
    *(float4*)(xout + i) = a;
}

// ---- fused: xout = x + p0 + p1; h = rmsnorm(xout)*g (one block per row) -----
__global__ __launch_bounds__(256) void addrednorm_k(float* __restrict__ xout,
                                                    const float* __restrict__ x,
                                                    const float* __restrict__ p0,
                                                    const float* __restrict__ p1,
                                                    const float* __restrict__ g,
                                                    u16* __restrict__ out) {
    const long row = blockIdx.x;
    const int tid = threadIdx.x;
    const long base = row * 2048;
    float4 a = *(const float4*)(x + base + tid * 4);
    float4 b = *(const float4*)(p0 + base + tid * 4);
    float4 c = *(const float4*)(p1 + base + tid * 4);
    a.x += b.x + c.x; a.y += b.y + c.y; a.z += b.z + c.z; a.w += b.w + c.w;
    float4 a2 = *(const float4*)(x + base + 1024 + tid * 4);
    float4 b2 = *(const float4*)(p0 + base + 1024 + tid * 4);
    float4 c2 = *(const float4*)(p1 + base + 1024 + tid * 4);
    a2.x += b2.x + c2.x; a2.y += b2.y + c2.y;
    a2.z += b2.z + c2.z; a2.w += b2.w + c2.w;
    *(float4*)(xout + base + tid * 4) = a;
    *(float4*)(xout + base + 1024 + tid * 4) = a2;
    float ss = a.x*a.x + a.y*a.y + a.z*a.z + a.w*a.w
             + a2.x*a2.x + a2.y*a2.y + a2.z*a2.z + a2.w*a2.w;
    #pragma unroll
    for (int d = 1; d < 64; d <<= 1) ss += __shfl_xor(ss, d);
    __shared__ float red[4];
    if ((tid & 63) == 0) red[tid >> 6] = ss;
    __syncthreads();
    float tot = red[0] + red[1] + red[2] + red[3];
    float rinv = rsqrtf(tot * (1.0f / 2048.0f) + 1e-6f);
    float4 g0 = *(const float4*)(g + tid * 4);
    float4 g1 = *(const float4*)(g + 1024 + tid * 4);
    u16x4 o0, o1;
    o0[0] = f2b(a.x * g0.x * rinv); o0[1] = f2b(a.y * g0.y * rinv);
    o0[2] = f2b(a.z * g0.z * rinv); o0[3] = f2b(a.w * g0.w * rinv);
    o1[0] = f2b(a2.x * g1.x * rinv); o1[1] = f2b(a2.y * g1.y * rinv);
    o1[2] = f2b(a2.z * g1.z * rinv); o1[3] = f2b(a2.w * g1.w * rinv);
    *(u16x4*)(out + base + tid * 4) = o0;
    *(u16x4*)(out + base + 1024 + tid * 4) = o1;
}

// ---------------- RMSNorm: fp32 in -> bf16 out (D=2048) ----------------------
__global__ __launch_bounds__(256) void rmsnorm_k(const float* __restrict__ x,
                                                 const float* __restrict__ g,
                                                 u16* __restrict__ out) {
    const long row = blockIdx.x;
    const int tid = threadIdx.x;
    const float* xr = x + row * 2048;
    float4 a = *(const float4*)(xr + tid * 4);
    float4 b = *(const float4*)(xr + 1024 + tid * 4);
    float ss = a.x*a.x + a.y*a.y + a.z*a.z + a.w*a.w
             + b.x*b.x + b.y*b.y + b.z*b.z + b.w*b.w;
    #pragma unroll
    for (int d = 1; d < 64; d <<= 1) ss += __shfl_xor(ss, d);
    __shared__ float red[4];
    if ((tid & 63) == 0) red[tid >> 6] = ss;
    __syncthreads();
    float tot = red[0] + red[1] + red[2] + red[3];
    float rinv = rsqrtf(tot * (1.0f / 2048.0f) + 1e-6f);
    float4 g0 = *(const float4*)(g + tid * 4);
    float4 g1 = *(const float4*)(g + 1024 + tid * 4);
    u16x4 o0, o1;
    o0[0] = f2b(a.x * g0.x * rinv); o0[1] = f2b(a.y * g0.y * rinv);
    o0[2] = f2b(a.z * g0.z * rinv); o0[3] = f2b(a.w * g0.w * rinv);
    o1[0] = f2b(b.x * g1.x * rinv); o1[1] = f2b(b.y * g1.y * rinv);
    o1[2] = f2b(b.z * g1.z * rinv); o1[3] = f2b(b.w * g1.w * rinv);
    *(u16x4*)(out + row * 2048 + tid * 4) = o0;
    *(u16x4*)(out + row * 2048 + 1024 + tid * 4) = o1;
}

// ---------------- RoPE in-place on bf16 qkv; q additionally scaled ------------
__global__ __launch_bounds__(256) void rope_k(u16* __restrict__ qkv,
                                              const float* __restrict__ cosb,
                                              const float* __restrict__ sinb) {
    long idx = (long)blockIdx.x * 256 + threadIdx.x;
    int d = (int)(idx & 15) * 4;
    int h = (int)((idx >> 4) & 15);
    int which = (int)((idx >> 8) & 1);
    long row = idx >> 9;
    int s = (int)(row & 2047);
    u16* base = qkv + row * 6144 + which * 2048 + h * 128;
    u16x4 ua = *(u16x4*)(base + d);
    u16x4 ub = *(u16x4*)(base + d + 64);
    float4 c4 = *(const float4*)(cosb + (long)s * 128 + d);
    float4 s4 = *(const float4*)(sinb + (long)s * 128 + d);
    float cc[4] = {c4.x, c4.y, c4.z, c4.w};
    float sn[4] = {s4.x, s4.y, s4.z, s4.w};
    float scale = (which == 0) ? 0.08838834764831845f : 1.0f;
    u16x4 oa, ob;
    #pragma unroll
    for (int j = 0; j < 4; ++j) {
        float a = b2f(ua[j]), b = b2f(ub[j]);
        oa[j] = f2b((a * cc[j] - b * sn[j]) * scale);
        ob[j] = f2b((b * cc[j] + a * sn[j]) * scale);
    }
    *(u16x4*)(base + d) = oa;
    *(u16x4*)(base + d + 64) = ob;
}

// ---------------- V transpose: qkv V section -> vt[bh][d][s] -----------------
__global__ __launch_bounds__(256) void vtrans_k(const u16* __restrict__ qkv,
                                                u16* __restrict__ vt) {
    __shared__ u16 t[128 * 65];
    const int bh = blockIdx.y, b = bh >> 4, h = bh & 15;
    const int s0 = blockIdx.x * 64;
    const int tid = threadIdx.x;
    #pragma unroll
    for (int it = 0; it < 4; ++it) {
        int flat = it * 256 + tid;
        int sl = flat >> 4, slot = flat & 15;
        u16x8 v = *(const u16x8*)(qkv + (long)(b * 2048 + s0 + sl) * 6144 + 4096 +
                                  h * 128 + slot * 8);
        #pragma unroll
        for (int j = 0; j < 8; ++j) t[(slot * 8 + j) * 65 + sl] = v[j];
    }
    __syncthreads();
    #pragma unroll
    for (int it = 0; it < 4; ++it) {
        int flat = it * 256 + tid;
        int d = flat >> 3, sg = flat & 7;
        u16x8 v;
        #pragma unroll
        for (int j = 0; j < 8; ++j) v[j] = t[d * 65 + sg * 8 + j];
        *(u16x8*)(vt + ((long)bh * 128 + d) * 2048 + s0 + sg * 8) = v;
    }
}

// ---------------- GEMM 256x256, 8-phase counted-vmcnt pipeline ---------------
#define DS_A(BUF, SM, KK) (*(const bf16x8*)(ldsb + (BUF)*32768 + \
        ((((SM)*2) + (KK)) << 10) + rin64 + cst2))
#define DS_B(BUF, SN, KK) (*(const bf16x8*)(ldsb + 65536 + (BUF)*32768 + \
        ((((SN)*2) + (KK)) << 10) + rin64 + cst2))
#define STAGE_A(BUF, SK, KT) do { \
    gload_lds16(sA0 + ((long)(KT)*64 + (SK)*32), ldsb + (BUF)*32768 + (w4 + (SK))*1024); \
    gload_lds16(sA1 + ((long)(KT)*64 + (SK)*32), ldsb + (BUF)*32768 + (w4 + 2 + (SK))*1024); \
} while (0)
#define STAGE_B(BUF, SK, KT) do { \
    gload_lds16(sB0 + ((long)(KT)*64 + (SK)*32), ldsb + 65536 + (BUF)*32768 + (w4 + (SK))*1024); \
    gload_lds16(sB1 + ((long)(KT)*64 + (SK)*32), ldsb + 65536 + (BUF)*32768 + (w4 + 2 + (SK))*1024); \
} while (0)
#define PHASE(BUF, MH, KK, RDB, STAGE_STMT, VM) do { \
    bf16x8 af[4]; \
    _Pragma("unroll") \
    for (int m = 0; m < 4; ++m) af[m] = DS_A(BUF, wr8 + (MH)*4 + m, KK); \
    if (RDB) { \
        bfr[0] = DS_B(BUF, wc4 + 0, KK); bfr[1] = DS_B(BUF, wc4 + 1, KK); \
        bfr[2] = DS_B(BUF, wc4 + 2, KK); bfr[3] = DS_B(BUF, wc4 + 3, KK); \
    } \
    STAGE_STMT; \
    if (VM) { asm volatile("s_waitcnt vmcnt(6)" ::: "memory"); } \
    __builtin_amdgcn_sched_barrier(0); \
    __builtin_amdgcn_s_barrier(); \
    __builtin_amdgcn_sched_barrier(0); \
    __builtin_amdgcn_s_setprio(1); \
    _Pragma("unroll") \
    for (int m = 0; m < 4; ++m) \
        _Pragma("unroll") \
        for (int n = 0; n < 4; ++n) \
            acc[(MH)*4 + m][n] = MFMA16(af[m], bfr[n], acc[(MH)*4 + m][n], 0, 0, 0); \
    __builtin_amdgcn_s_setprio(0); \
    __builtin_amdgcn_sched_barrier(0); \
    __builtin_amdgcn_s_barrier(); \
    __builtin_amdgcn_sched_barrier(0); \
} while (0)

template <int EPI>
__global__ __launch_bounds__(512, 2) void gemm256(const u16* __restrict__ A,
                                                  const u16* __restrict__ W,
                                                  int M, int N, int K,
                                                  u16* outb, float* outf,
                                                  const float* res, int ksplit) {
    __shared__ u16 lds_[65536];
    char* ldsb = (char*)lds_;
    const int tid = threadIdx.x;
    const int w = tid >> 6, l = tid & 63;
    const int w4 = w * 4;
    const int wr8 = (w >> 2) * 8;
    const int wc4 = (w & 3) * 4;
    const int rin64 = (l & 15) * 64;
    const int cst2 = ((((l >> 4) * 8) ^ (((l >> 3) & 1) << 4)) << 1);

    const int nbn = N >> 8;
    const int nbm = M >> 8;
    const int nwg = gridDim.x;
    const int cpx = nwg >> 3;
    const int bid = blockIdx.x;
    int wg = (bid & 7) * cpx + (bid >> 3);
    int kseg = 0;
    int Keff = K;
    if (ksplit == 2) {
        kseg = wg & 1;
        wg >>= 1;
        Keff = K >> 1;
    }
    const int grp = 8 * nbn;
    const int g8 = wg / grp;
    const int rem = wg - g8 * grp;
    const int bm0 = g8 * 8;
    const int gmh = (nbm - bm0 < 8) ? (nbm - bm0) : 8;
    const int bn = rem / gmh;
    const int bm = bm0 + rem % gmh;
    const u16* Ab = A + (long)kseg * Keff;
    const u16* Wb = W + (long)kseg * Keff;

    const int r4 = l >> 2;
    const int clog = ((l & 3) * 8) ^ (((r4 >> 3) & 1) << 4);
    const u16* sA0 = Ab + ((long)bm * 256 + (w * 2 + 0) * 16 + r4) * K + clog;
    const u16* sA1 = Ab + ((long)bm * 256 + (w * 2 + 1) * 16 + r4) * K + clog;
    const u16* sB0 = Wb + ((long)bn * 256 + (w * 2 + 0) * 16 + r4) * K + clog;
    const u16* sB1 = Wb + ((long)bn * 256 + (w * 2 + 1) * 16 + r4) * K + clog;

    f32x4 acc[8][4];
    #pragma unroll
    for (int m = 0; m < 8; ++m)
        #pragma unroll
        for (int n = 0; n < 4; ++n) acc[m][n] = (f32x4){0.f, 0.f, 0.f, 0.f};
    bf16x8 bfr[4];

    const int nkt = Keff >> 6;
    const int niter = nkt >> 1;

    STAGE_B(0, 0, 0); STAGE_A(0, 0, 0); STAGE_B(0, 1, 0); STAGE_A(0, 1, 0);
    STAGE_B(1, 0, 1); STAGE_A(1, 0, 1); STAGE_B(1, 1, 1);
    asm volatile("s_waitcnt vmcnt(6)" ::: "memory");
    __builtin_amdgcn_sched_barrier(0);
    __builtin_amdgcn_s_barrier();
    __builtin_amdgcn_sched_barrier(0);

    for (int it = 0; it < niter; ++it) {
        const int t = it * 2;
        const int t1 = t + 1;
        const int t2 = (t + 2 < nkt) ? t + 2 : nkt - 1;
        const int t3 = (t + 3 < nkt) ? t + 3 : nkt - 1;
        PHASE(0, 0, 0, 1, STAGE_A(1, 1, t1), 0);
        PHASE(0, 1, 0, 0, STAGE_B(0, 0, t2), 0);
        PHASE(0, 0, 1, 1, STAGE_A(0, 0, t2), 0);
        PHASE(0, 1, 1, 0, STAGE_B(0, 1, t2), 1);
        PHASE(1, 0, 0, 1, STAGE_A(0, 1, t2), 0);
        PHASE(1, 1, 0, 0, STAGE_B(1, 0, t3), 0);
        PHASE(1, 0, 1, 1, STAGE_A(1, 0, t3), 0);
        PHASE(1, 1, 1, 0, STAGE_B(1, 1, t3), 1);
    }
    asm volatile("s_waitcnt vmcnt(0)" ::: "memory");

    const int rb = bm * 256 + (wr8 >> 3) * 128 + ((l >> 4) << 2);
    const int cb = bn * 256 + (w & 3) * 64 + (l & 15);
    float* pf = (EPI == 3) ? (outf + (long)kseg * M * N) : outf;
    #pragma unroll
    for (int m = 0; m < 8; ++m) {
        #pragma unroll
        for (int r = 0; r < 4; ++r) {
            long row = rb + m * 16 + r;
            #pragma unroll
            for (int n = 0; n < 4; ++n) {
                long col = cb + n * 16;
                float v = acc[m][n][r];
                if (EPI == 1) {
                    pf[row * N + col] = res[row * N + col] + v;
                } else if (EPI == 2) {
                    float u = 0.7978845608028654f * v * (1.0f + 0.044715f * v * v);
                    float e = __expf(2.0f * u);
                    float tgl = 1.0f - 2.0f / (e + 1.0f);
                    outb[row * N + col] = f2b(0.5f * v * (1.0f + tgl));
                } else if (EPI == 3) {
                    pf[row * N + col] = v;
                } else {
                    outb[row * N + col] = f2b(v);
                }
            }
        }
    }
}

// ---------------- causal flash attention v3 ----------------------------------
// 4 waves/block, QBLK=128 (wave owns 32 q rows), KVBLK=64, double-buffered
// K/V LDS with counted vmcnt(8) (T3/T4 minimal 2-phase).
struct AttnState {
    f32x16 acc[4];
    float m_i, l_i;
};

template <bool DIAG>
static __device__ __forceinline__ void attn_tile(
    int kv0, int qg, bool do_g1, int l31, int hi,
    const u16* __restrict__ Ks, const u16* __restrict__ Vt,
    const bf16x8 (&qf)[8], AttnState& st)
{
    f32x16 sacc0, sacc1;
    #pragma unroll
    for (int r = 0; r < 16; ++r) { sacc0[r] = 0.f; sacc1[r] = 0.f; }

    #pragma unroll
    for (int dsl = 0; dsl < 8; ++dsl) {
        int slot = dsl * 2 + hi;
        int kv = l31;
        int sw = (slot & 8) | ((slot & 7) ^ (kv & 7));
        bf16x8 kf = *(const bf16x8*)(Ks + kv * 128 + sw * 8);
        sacc0 = MFMA32(kf, qf[dsl], sacc0, 0, 0, 0);
    }
    if (do_g1) {
        #pragma unroll
        for (int dsl = 0; dsl < 8; ++dsl) {
            int slot = dsl * 2 + hi;
            int kv = 32 + l31;
            int sw = (slot & 8) | ((slot & 7) ^ (kv & 7));
            bf16x8 kf = *(const bf16x8*)(Ks + kv * 128 + sw * 8);
            sacc1 = MFMA32(kf, qf[dsl], sacc1, 0, 0, 0);
        }
    }

    float sv[2][16];
    #pragma unroll
    for (int r = 0; r < 16; ++r) {
        sv[0][r] = sacc0[r];
        sv[1][r] = do_g1 ? sacc1[r] : -INFINITY;
    }
    if (DIAG) {
        #pragma unroll
        for (int g = 0; g < 2; ++g)
            #pragma unroll
            for (int r = 0; r < 16; ++r) {
                int kvg = kv0 + g * 32 + ((r & 3) + 8 * (r >> 2) + 4 * hi);
                if (kvg > qg) sv[g][r] = -INFINITY;
            }
    }

    float mx = sv[0][0];
    #pragma unroll
    for (int r = 1; r < 16; ++r) mx = fmaxf(mx, sv[0][r]);
    #pragma unroll
    for (int r = 0; r < 16; ++r) mx = fmaxf(mx, sv[1][r]);
    mx = fmaxf(mx, __shfl_xor(mx, 32));

    bool defer = __all(mx <= st.m_i + 8.0f);
    if (!defer) {
        float mnew = fmaxf(st.m_i, mx);
        float f = __expf(st.m_i - mnew);
        st.l_i *= f;
        #pragma unroll
        for (int dblk = 0; dblk < 4; ++dblk)
            #pragma unroll
            for (int r = 0; r < 16; ++r) st.acc[dblk][r] *= f;
        st.m_i = mnew;
    }

    float ssum = 0.f;
    #pragma unroll
    for (int g = 0; g < 2; ++g)
        #pragma unroll
        for (int r = 0; r < 16; ++r) {
            float e = __expf(sv[g][r] - st.m_i);
            sv[g][r] = e;
            ssum += e;
        }
    ssum += __shfl_xor(ssum, 32);
    st.l_i += ssum;

    unsigned w[2][4][2];
    #pragma unroll
    for (int g = 0; g < 2; ++g)
        #pragma unroll
        for (int q4 = 0; q4 < 4; ++q4) {
            w[g][q4][0] = pk2(sv[g][4 * q4 + 0], sv[g][4 * q4 + 1]);
            w[g][q4][1] = pk2(sv[g][4 * q4 + 2], sv[g][4 * q4 + 3]);
        }
    bf16x8 pfrag[4];
    #pragma unroll
    for (int ks = 0; ks < 4; ++ks) {
        int g = ks >> 1, h2 = ks & 1;
        unsigned o0 = hi ? w[g][2 * h2 + 1][0] : w[g][2 * h2][0];
        unsigned o1 = hi ? w[g][2 * h2 + 1][1] : w[g][2 * h2][1];
        unsigned t0 = hi ? w[g][2 * h2][0] : w[g][2 * h2 + 1][0];
        unsigned t1 = hi ? w[g][2 * h2][1] : w[g][2 * h2 + 1][1];
        unsigned s0v = __shfl_xor(t0, 32);
        unsigned s1v = __shfl_xor(t1, 32);
        union { unsigned u[4]; bf16x8 v; } cv;
        cv.u[0] = hi ? s0v : o0;
        cv.u[1] = hi ? s1v : o1;
        cv.u[2] = hi ? o0 : s0v;
        cv.u[3] = hi ? o1 : s1v;
        pfrag[ks] = cv.v;
    }

    #pragma unroll
    for (int dblk = 0; dblk < 4; ++dblk) {
        int d = dblk * 32 + l31;
        #pragma unroll
        for (int ks = 0; ks < 4; ++ks) {
            if (ks >= 2 && !do_g1) continue;
            int slot = ks * 2 + hi;
            bf16x8 vf = *(const bf16x8*)(Vt + d * 64 + (slot ^ (d & 7)) * 8);
            st.acc[dblk] = MFMA32(vf, pfrag[ks], st.acc[dblk], 0, 0, 0);
        }
    }
}

__global__ __launch_bounds__(256) void attn3_k(const u16* __restrict__ qkv,
                                               const u16* __restrict__ vt,
                                               u16* __restrict__ out) {
    const int bh = blockIdx.y;
    const int b = bh >> 4, h = bh & 15;
    const int qb = blockIdx.x;
    const int q0 = qb * 128;
    const int tid = threadIdx.x, wave = tid >> 6, lane = tid & 63;
    const int l31 = lane & 31, hi = lane >> 5;
    const int brow = b * 2048;
    __shared__ u16 Ks_lds[2][64 * 128];
    __shared__ u16 Vt_lds[2][128 * 64];

    // per-thread staging constants
    const int krow = tid >> 4;            // 0..15 (K rows per 16-thread group)
    const int kslot = tid & 15;
    const int vrow = tid >> 3;            // 0..31 (V rows per 8-thread group)
    const int vslot = tid & 7;

    bf16x8 qf[8];
    {
        const u16* qp = qkv + (long)(brow + q0 + wave * 32 + l31) * 6144 +
                        h * 128 + hi * 8;
        #pragma unroll
        for (int dsl = 0; dsl < 8; ++dsl) qf[dsl] = *(const bf16x8*)(qp + dsl * 16);
    }

    AttnState st;
    st.m_i = -INFINITY; st.l_i = 0.f;
    #pragma unroll
    for (int dblk = 0; dblk < 4; ++dblk)
        #pragma unroll
        for (int r = 0; r < 16; ++r) st.acc[dblk][r] = 0.f;

    const int r0 = q0 + wave * 32;
    const int qg = r0 + l31;
    const int nt = 2 * qb + 2;
    int cur = 0;

#define STAGE_KV(BUF, KV0) do { \
    _Pragma("unroll") \
    for (int i = 0; i < 4; ++i) { \
        int kv = i * 16 + krow; \
        int sw = (kslot & 8) | ((kslot & 7) ^ (kv & 7)); \
        const u16* src = qkv + (long)(brow + (KV0) + kv) * 6144 + 2048 + \
                         h * 128 + sw * 8; \
        gload_lds16(src, (char*)Ks_lds[BUF] + (i * 16 + wave * 4) * 256); \
    } \
    _Pragma("unroll") \
    for (int i = 0; i < 4; ++i) { \
        int d = i * 32 + vrow; \
        int sw = vslot ^ (d & 7); \
        const u16* src = vt + ((long)bh * 128 + d) * 2048 + (KV0) + sw * 8; \
        gload_lds16(src, (char*)Vt_lds[BUF] + (i * 32 + wave * 8) * 128); \
    } \
} while (0)

    STAGE_KV(0, 0);
    for (int t = 0; t < nt; ++t) {
        const int kv0 = t * 64;
        const bool more = (t + 1 < nt);
        if (more) {
            if (cur) STAGE_KV(0, kv0 + 64); else STAGE_KV(1, kv0 + 64);
        }
        if (more) { asm volatile("s_waitcnt vmcnt(8)" ::: "memory"); }
        else      { asm volatile("s_waitcnt vmcnt(0)" ::: "memory"); }
        __builtin_amdgcn_sched_barrier(0);
        __builtin_amdgcn_s_barrier();
        __builtin_amdgcn_sched_barrier(0);
        {
            const u16* Ks = Ks_lds[cur];
            const u16* Vt_ = Vt_lds[cur];
            const int delta = r0 - kv0;
            if (delta >= 64)
                attn_tile<false>(kv0, qg, true, l31, hi, Ks, Vt_, qf, st);
            else if (delta >= 0)
                attn_tile<true>(kv0, qg, delta >= 32, l31, hi, Ks, Vt_, qf, st);
            // delta <= -32: fully masked, idle through barriers
        }
        __builtin_amdgcn_sched_barrier(0);
        __builtin_amdgcn_s_barrier();
        __builtin_amdgcn_sched_barrier(0);
        cur ^= 1;
    }
#undef STAGE_KV

    float inv = 1.0f / st.l_i;
    long orow = (long)(brow + q0 + wave * 32 + l31);
    #pragma unroll
    for (int dblk = 0; dblk < 4; ++dblk)
        #pragma unroll
        for (int rq = 0; rq < 4; ++rq) {
            u16x4 o4;
            #pragma unroll
            for (int m = 0; m < 4; ++m) o4[m] = f2b(st.acc[dblk][rq * 4 + m] * inv);
            int d = dblk * 32 + 8 * rq + 4 * hi;
            *(u16x4*)(out + orow * 2048 + h * 128 + d) = o4;
        }
}

// ---------------- launch --------------------------------------------------
extern "C" void kernel_launch(void* const* d_in, const int* in_sizes, int n_in,
                              void* d_out, int out_size, void* d_ws, size_t ws_size,
                              hipStream_t stream) {
    const float* x     = (const float*)d_in[0];
    const float* cosb  = (const float*)d_in[1];
    const float* sinb  = (const float*)d_in[2];
    const float* g1    = (const float*)d_in[3];
    const float* g2    = (const float*)d_in[4];
    const float* w_qkv = (const float*)d_in[5];
    const float* w_out = (const float*)d_in[6];
    const float* w_fc1 = (const float*)d_in[7];
    const float* w_fc2 = (const float*)d_in[8];

    char* ws = (char*)d_ws;
    u16* wqkv_b = (u16*)(ws);                    // 6144x2048 bf16
    u16* wout_b = (u16*)(ws + 25165824);         // 2048x2048
    u16* wfc1_b = (u16*)(ws + 33554432);         // 8192x2048
    u16* wfc2_b = (u16*)(ws + 67108864);         // 2048x8192
    u16* h_b    = (u16*)(ws + 100663296);        // 4096x2048 (h1 / vt / h2)
    u16* qkv_b  = (u16*)(ws + 117440512);        // 4096x6144
    u16* attn_b = (u16*)(ws + 167772160);        // 4096x2048
    u16* vt_b   = h_b;                           // 32x128x2048 (after qkv GEMM)
    u16* hg_b   = qkv_b;                         // 4096x8192, reuses qkv+attn
    float* part = (float*)ws;                    // fc2 split-K partials (dead w*)
    float* pop  = (float*)(ws + 100663296);      // out-proj partials (dead h/qkv)
    float* xout = (float*)d_out;

    cvt_k<<<12288, 256, 0, stream>>>(w_qkv, wqkv_b, 12582912L);
    cvt_k<<<4096, 256, 0, stream>>>(w_out, wout_b, 4194304L);
    cvt_k<<<16384, 256, 0, stream>>>(w_fc1, wfc1_b, 16777216L);
    cvt_k<<<16384, 256, 0, stream>>>(w_fc2, wfc2_b, 16777216L);

    rmsnorm_k<<<4096, 256, 0, stream>>>(x, g1, h_b);
    gemm256<0><<<384, 512, 0, stream>>>(h_b, wqkv_b, 4096, 6144, 2048,
                                        qkv_b, nullptr, nullptr, 1);
    rope_k<<<8192, 256, 0, stream>>>(qkv_b, cosb, sinb);
    vtrans_k<<<dim3(32, 32), 256, 0, stream>>>(qkv_b, vt_b);
    attn3_k<<<dim3(16, 32), 256, 0, stream>>>(qkv_b, vt_b, attn_b);
    gemm256<3><<<256, 512, 0, stream>>>(attn_b, wout_b, 4096, 2048, 2048,
                                        nullptr, pop, nullptr, 2);
    addrednorm_k<<<4096, 256, 0, stream>>>(xout, x, pop, pop + 8388608, g2, h_b);
    gemm256<2><<<512, 512, 0, stream>>>(h_b, wfc1_b, 4096, 8192, 2048,
                                        hg_b, nullptr, nullptr, 1);
    gemm256<3><<<256, 512, 0, stream>>>(hg_b, wfc2_b, 4096, 2048, 8192,
                                        nullptr, part, nullptr, 2);
    addred_k<<<8192, 256, 0, stream>>>(xout, part, part + 8388608);
}